// Round 12
// baseline (1615.183 us; speedup 1.0000x reference)
//
#include <hip/hip_runtime.h>
#include <math.h>

#define D 128
#define NG 64
#define NG2 128
#define NSTEPS 5

using short8 = __attribute__((ext_vector_type(8))) short;
using f32x4  = __attribute__((ext_vector_type(4))) float;
using f32x2  = __attribute__((ext_vector_type(2))) float;

// fast, overflow-safe transcendentals (v_exp_f32 + v_rcp_f32)
__device__ __forceinline__ float sigf(float x) {
  float e = __expf(-fabsf(x));
  float inv = __fdividef(1.f, 1.f + e);
  return x >= 0.f ? inv : e * inv;
}
__device__ __forceinline__ float tanhf_fast(float x) {
  float e = __expf(-2.f * fabsf(x));
  float r = (1.f - e) * __fdividef(1.f, 1.f + e);
  return x >= 0.f ? r : -r;
}
__device__ __forceinline__ float lrelu(float x) { return x > 0.f ? x : 0.2f * x; }
__device__ __forceinline__ short f2bf(float x) {
  unsigned u = __float_as_uint(x);
  u += 0x7fff + ((u >> 16) & 1);
  return (short)(u >> 16);
}
__device__ __forceinline__ unsigned pk2(float x, float y) {
  return ((unsigned)(unsigned short)f2bf(y) << 16) | (unsigned short)f2bf(x);
}
__device__ __forceinline__ float bflo(unsigned v) { return __uint_as_float(v << 16); }
__device__ __forceinline__ float bfhi(unsigned v) { return __uint_as_float(v & 0xffff0000u); }
__device__ __forceinline__ float bf2f(short s) {
  return __uint_as_float(((unsigned)(unsigned short)s) << 16);
}
__device__ __forceinline__ unsigned char f2fp8(float x) {
  int p = __builtin_amdgcn_cvt_pk_fp8_f32(x, x, 0, false);
  return (unsigned char)(p & 0xff);
}

// ---------- init: concat(in_feat1,in_feat2) -> hb (bf16) ----------
__global__ void k_init(const float* __restrict__ f1, const float* __restrict__ f2,
                       short* __restrict__ hb, int Nd4) {
  int tot = 2 * Nd4;
  for (int i = blockIdx.x * blockDim.x + threadIdx.x; i < tot; i += gridDim.x * blockDim.x) {
    float4 v = (i < Nd4) ? ((const float4*)f1)[i] : ((const float4*)f2)[i - Nd4];
    ((uint2*)hb)[i] = make_uint2(pk2(v.x, v.y), pk2(v.z, v.w));
  }
}

// ---------- pack W[NC][128] into MFMA b-frag order, K=128 ----------
__global__ void k_pack(const float* __restrict__ W, short* __restrict__ P, int NC) {
  int n = NC * 128;
  for (int i = blockIdx.x * blockDim.x + threadIdx.x; i < n; i += gridDim.x * blockDim.x) {
    int j = i & 7;
    int lane = (i >> 3) & 63;
    int kt = (i >> 9) & 3;
    int nt = i >> 11;
    int c = nt * 16 + (lane & 15);
    int k = kt * 32 + ((lane >> 4) << 3) + j;
    P[i] = f2bf(W[c * 128 + k]);
  }
}

// ---------- fused weight: Wcomb[g][k] = sum_d W_ih[g][d]*W_et[k>>7][d][k&127],
// packed directly into MFMA b-frag order (K=512, 24 col tiles) ----------
__global__ void k_packComb(const float* __restrict__ W_ih, const float* __restrict__ W_et,
                           short* __restrict__ P) {
  int n = 384 * 512;
  for (int i = blockIdx.x * blockDim.x + threadIdx.x; i < n; i += gridDim.x * blockDim.x) {
    int j = i & 7;
    int lane = (i >> 3) & 63;
    int kt = (i >> 9) & 15;
    int nt = i >> 13;
    int g = nt * 16 + (lane & 15);
    int k = kt * 32 + ((lane >> 4) << 3) + j;
    int et = k >> 7, kk = k & 127;
    float s = 0.f;
    #pragma unroll 4
    for (int d = 0; d < 128; ++d)
      s += W_ih[g * 128 + d] * W_et[et * 16384 + d * 128 + kk];
    P[i] = f2bf(s);
  }
}

// ---------- Bc[et][g] = sum_d W_ih[g][d]*b_et[et][d] ----------
__global__ void k_bc(const float* __restrict__ W_ih, const float* __restrict__ b_et,
                     float* __restrict__ Bc) {
  int i = blockIdx.x * 256 + threadIdx.x;
  if (i >= 4 * 384) return;
  int et = i / 384, g = i - et * 384;
  float s = 0.f;
  #pragma unroll 4
  for (int d = 0; d < 128; ++d) s += W_ih[g * 128 + d] * b_et[et * 128 + d];
  Bc[et * 384 + g] = s;
}

// ---------- CSR build over merged graph ----------
__global__ void k_hist(const int* __restrict__ dst1, const int* __restrict__ dst2,
                       int E, int N, int* __restrict__ deg) {
  for (int e = blockIdx.x * blockDim.x + threadIdx.x; e < 2 * E; e += gridDim.x * blockDim.x) {
    int d = (e < E) ? dst1[e] : dst2[e - E] + N;
    atomicAdd(&deg[d], 1);
  }
}

__global__ __launch_bounds__(256) void k_scan_a(const int* __restrict__ deg, int n,
                                                int* __restrict__ bsum) {
  int base = blockIdx.x * 1024 + threadIdx.x * 4;
  int s = 0;
  if (base + 3 < n) {
    int4 v = *(const int4*)(deg + base);
    s = v.x + v.y + v.z + v.w;
  } else {
    for (int k = 0; k < 4; ++k) if (base + k < n) s += deg[base + k];
  }
  #pragma unroll
  for (int off = 32; off; off >>= 1) s += __shfl_xor(s, off);
  __shared__ int ws[4];
  if ((threadIdx.x & 63) == 0) ws[threadIdx.x >> 6] = s;
  __syncthreads();
  if (threadIdx.x == 0) bsum[blockIdx.x] = ws[0] + ws[1] + ws[2] + ws[3];
}

__global__ __launch_bounds__(1024) void k_scan_b(const int* __restrict__ bsum,
                                                 int* __restrict__ boffs, int nb) {
  int tid = threadIdx.x;
  int v = (tid < nb) ? bsum[tid] : 0;
  int lane = tid & 63, wv = tid >> 6;
  int x = v;
  #pragma unroll
  for (int off = 1; off < 64; off <<= 1) {
    int y = __shfl_up(x, off);
    if (lane >= off) x += y;
  }
  __shared__ int wsum[16];
  if (lane == 63) wsum[wv] = x;
  __syncthreads();
  if (tid < 16) {
    int u = wsum[tid];
    #pragma unroll
    for (int off = 1; off < 16; off <<= 1) {
      int y = __shfl_up(u, off);
      if (tid >= off) u += y;
    }
    wsum[tid] = u;
  }
  __syncthreads();
  int woff = wv ? wsum[wv - 1] : 0;
  if (tid < nb) boffs[tid] = woff + x - v;
}

__global__ __launch_bounds__(256) void k_scan_c(const int* __restrict__ deg,
    const int* __restrict__ boffs, int* __restrict__ row_ofs,
    int* __restrict__ cursor, int n) {
  int base = blockIdx.x * 1024 + threadIdx.x * 4;
  int v[4] = {0, 0, 0, 0};
  if (base + 3 < n) {
    int4 t = *(const int4*)(deg + base);
    v[0] = t.x; v[1] = t.y; v[2] = t.z; v[3] = t.w;
  } else {
    for (int k = 0; k < 4; ++k) if (base + k < n) v[k] = deg[base + k];
  }
  int s = v[0] + v[1] + v[2] + v[3];
  int lane = threadIdx.x & 63, wv = threadIdx.x >> 6;
  int x = s;
  #pragma unroll
  for (int off = 1; off < 64; off <<= 1) {
    int y = __shfl_up(x, off);
    if (lane >= off) x += y;
  }
  __shared__ int wsum[4];
  if (lane == 63) wsum[wv] = x;
  __syncthreads();
  int woff = 0;
  for (int w = 0; w < wv; ++w) woff += wsum[w];
  int run = boffs[blockIdx.x] + woff + x - s;
  #pragma unroll
  for (int k = 0; k < 4; ++k) {
    int i = base + k;
    if (i < n) {
      cursor[i] = run;
      run += v[k];
      row_ofs[i + 1] = run;
    }
  }
  if (blockIdx.x == 0 && threadIdx.x == 0) row_ofs[0] = 0;
}

// scatter: single merged array csr_se = src*4 + etype
__global__ void k_scatter(const int* __restrict__ src1, const int* __restrict__ dst1,
                          const int* __restrict__ ety1, const int* __restrict__ src2,
                          const int* __restrict__ dst2, const int* __restrict__ ety2,
                          int E, int N, int* __restrict__ cursor,
                          int* __restrict__ csr_se) {
  for (int e = blockIdx.x * blockDim.x + threadIdx.x; e < 2 * E; e += gridDim.x * blockDim.x) {
    int s, d, et;
    if (e < E) { s = src1[e]; d = dst1[e]; et = ety1[e]; }
    else { s = src2[e - E] + N; d = dst2[e - E] + N; et = ety2[e - E]; }
    int p = atomicAdd(&cursor[d], 1);
    csr_se[p] = s * 4 + et;
  }
}

// ---------- merged gid array [2N] + per-graph counts [128] ----------
__global__ void k_fillgid(const int* __restrict__ gid1, const int* __restrict__ gid2,
                          int N, int* __restrict__ gidc, int* __restrict__ gcnt) {
  __shared__ int cnt[NG2];
  int t = threadIdx.x;
  if (t < NG2) cnt[t] = 0;
  __syncthreads();
  int i = blockIdx.x * 256 + t;
  if (i < 2 * N) {
    int g = (i < N) ? gid1[i] : gid2[i - N] + NG;
    gidc[i] = g;
    atomicAdd(&cnt[g], 1);
  }
  __syncthreads();
  if (t < NG2 && cnt[t]) atomicAdd(&gcnt[t], cnt[t]);
}

// ---------- per-etype neighbor sums + counts; readlane broadcast + 8x MLP ----------
__global__ __launch_bounds__(256) void k_aggS(const short* __restrict__ hb,
    const int* __restrict__ row_ofs, const int* __restrict__ csr_se,
    short* __restrict__ S, float* __restrict__ cntf, int N) {
  int node = blockIdx.x * 4 + (threadIdx.x >> 6);
  int lane = threadIdx.x & 63;
  if (node >= N) return;
  int beg = row_ofs[node], end = row_ofs[node + 1];
  float a0x = 0.f, a0y = 0.f, a1x = 0.f, a1y = 0.f;
  float a2x = 0.f, a2y = 0.f, a3x = 0.f, a3y = 0.f;
  int c0 = 0, c1 = 0, c2 = 0, c3 = 0;
  #define ACC(ET, VX, VY) do { \
      if (ET == 0)      { a0x += VX; a0y += VY; ++c0; } \
      else if (ET == 1) { a1x += VX; a1y += VY; ++c1; } \
      else if (ET == 2) { a2x += VX; a2y += VY; ++c2; } \
      else              { a3x += VX; a3y += VY; ++c3; } } while (0)
  for (int base = beg; base < end; base += 64) {
    int nv = end - base; if (nv > 64) nv = 64;
    int r = (lane < nv) ? csr_se[base + lane] : 0;
    int j = 0;
    for (; j + 8 <= nv; j += 8) {
      int rr0 = __builtin_amdgcn_readlane(r, j + 0);
      int rr1 = __builtin_amdgcn_readlane(r, j + 1);
      int rr2 = __builtin_amdgcn_readlane(r, j + 2);
      int rr3 = __builtin_amdgcn_readlane(r, j + 3);
      int rr4 = __builtin_amdgcn_readlane(r, j + 4);
      int rr5 = __builtin_amdgcn_readlane(r, j + 5);
      int rr6 = __builtin_amdgcn_readlane(r, j + 6);
      int rr7 = __builtin_amdgcn_readlane(r, j + 7);
      unsigned v0 = ((const unsigned*)(hb + (size_t)(rr0 >> 2) * 128))[lane];
      unsigned v1 = ((const unsigned*)(hb + (size_t)(rr1 >> 2) * 128))[lane];
      unsigned v2 = ((const unsigned*)(hb + (size_t)(rr2 >> 2) * 128))[lane];
      unsigned v3 = ((const unsigned*)(hb + (size_t)(rr3 >> 2) * 128))[lane];
      unsigned v4 = ((const unsigned*)(hb + (size_t)(rr4 >> 2) * 128))[lane];
      unsigned v5 = ((const unsigned*)(hb + (size_t)(rr5 >> 2) * 128))[lane];
      unsigned v6 = ((const unsigned*)(hb + (size_t)(rr6 >> 2) * 128))[lane];
      unsigned v7 = ((const unsigned*)(hb + (size_t)(rr7 >> 2) * 128))[lane];
      ACC(rr0 & 3, bflo(v0), bfhi(v0));
      ACC(rr1 & 3, bflo(v1), bfhi(v1));
      ACC(rr2 & 3, bflo(v2), bfhi(v2));
      ACC(rr3 & 3, bflo(v3), bfhi(v3));
      ACC(rr4 & 3, bflo(v4), bfhi(v4));
      ACC(rr5 & 3, bflo(v5), bfhi(v5));
      ACC(rr6 & 3, bflo(v6), bfhi(v6));
      ACC(rr7 & 3, bflo(v7), bfhi(v7));
    }
    for (; j < nv; ++j) {
      int rr = __builtin_amdgcn_readlane(r, j);
      unsigned v = ((const unsigned*)(hb + (size_t)(rr >> 2) * 128))[lane];
      ACC(rr & 3, bflo(v), bfhi(v));
    }
  }
  #undef ACC
  size_t b = (size_t)node * 512;
  ((unsigned*)(S + b      ))[lane] = pk2(a0x, a0y);
  ((unsigned*)(S + b + 128))[lane] = pk2(a1x, a1y);
  ((unsigned*)(S + b + 256))[lane] = pk2(a2x, a2y);
  ((unsigned*)(S + b + 384))[lane] = pk2(a3x, a3y);
  if (lane == 0) {
    float4 cv = {(float)c0, (float)c1, (float)c2, (float)c3};
    *(float4*)(cntf + (size_t)node * 4) = cv;
  }
}

// ---------- FUSED message-GEMM + GRU: gi = S @ Wcomb (K=512), gh = h @ Whh (K=128) ----------
__global__ __launch_bounds__(256) void k_gru2(const short* __restrict__ S,
    short* __restrict__ hb, const float* __restrict__ cntf,
    const short* __restrict__ WcombP, const short* __restrict__ WhhP,
    const float* __restrict__ Bc, const float* __restrict__ b_ih,
    const float* __restrict__ b_hh, int M) {
  int tid = threadIdx.x;
  int lane = tid & 63, wave = tid >> 6;
  int row0 = blockIdx.x * 64 + wave * 16;
  int quad = lane >> 4, l15 = lane & 15;
  int ar = row0 + l15; if (ar >= M) ar = M - 1;
  short8 sf[16];
  #pragma unroll
  for (int kt = 0; kt < 16; ++kt)
    sf[kt] = *(const short8*)(S + (size_t)ar * 512 + kt * 32 + quad * 8);
  short8 fh[4];
  #pragma unroll
  for (int kt = 0; kt < 4; ++kt)
    fh[kt] = *(const short8*)(hb + (size_t)ar * 128 + kt * 32 + quad * 8);
  float4 cn[4];
  #pragma unroll
  for (int reg = 0; reg < 4; ++reg) {
    int r = row0 + quad * 4 + reg; if (r >= M) r = M - 1;
    cn[reg] = *(const float4*)(cntf + (size_t)r * 4);
  }
  size_t li = (size_t)lane * 8;
  for (int nt = 0; nt < 8; ++nt) {
    f32x4 air = {0.f,0.f,0.f,0.f}, aiz = {0.f,0.f,0.f,0.f}, ain = {0.f,0.f,0.f,0.f};
    f32x4 ahr = {0.f,0.f,0.f,0.f}, ahz = {0.f,0.f,0.f,0.f}, ahn = {0.f,0.f,0.f,0.f};
    #pragma unroll
    for (int kt = 0; kt < 16; ++kt) {
      short8 br = *(const short8*)(WcombP + ((size_t)((nt     ) * 16 + kt) * 64) * 8 + li);
      short8 bz = *(const short8*)(WcombP + ((size_t)((nt +  8) * 16 + kt) * 64) * 8 + li);
      short8 bn = *(const short8*)(WcombP + ((size_t)((nt + 16) * 16 + kt) * 64) * 8 + li);
      air = __builtin_amdgcn_mfma_f32_16x16x32_bf16(sf[kt], br, air, 0, 0, 0);
      aiz = __builtin_amdgcn_mfma_f32_16x16x32_bf16(sf[kt], bz, aiz, 0, 0, 0);
      ain = __builtin_amdgcn_mfma_f32_16x16x32_bf16(sf[kt], bn, ain, 0, 0, 0);
    }
    #pragma unroll
    for (int kt = 0; kt < 4; ++kt) {
      short8 ur = *(const short8*)(WhhP + ((size_t)((nt     ) * 4 + kt) * 64) * 8 + li);
      short8 uz = *(const short8*)(WhhP + ((size_t)((nt +  8) * 4 + kt) * 64) * 8 + li);
      short8 un = *(const short8*)(WhhP + ((size_t)((nt + 16) * 4 + kt) * 64) * 8 + li);
      ahr = __builtin_amdgcn_mfma_f32_16x16x32_bf16(fh[kt], ur, ahr, 0, 0, 0);
      ahz = __builtin_amdgcn_mfma_f32_16x16x32_bf16(fh[kt], uz, ahz, 0, 0, 0);
      ahn = __builtin_amdgcn_mfma_f32_16x16x32_bf16(fh[kt], un, ahn, 0, 0, 0);
    }
    int c = nt * 16 + l15;
    float bir = b_ih[c],      bhr = b_hh[c];
    float biz = b_ih[c+128],  bhz = b_hh[c+128];
    float bin_= b_ih[c+256],  bhn = b_hh[c+256];
    float bcr0 = Bc[c],       bcr1 = Bc[384+c],  bcr2 = Bc[768+c],  bcr3 = Bc[1152+c];
    float bcz0 = Bc[128+c],   bcz1 = Bc[512+c],  bcz2 = Bc[896+c],  bcz3 = Bc[1280+c];
    float bcn0 = Bc[256+c],   bcn1 = Bc[640+c],  bcn2 = Bc[1024+c], bcn3 = Bc[1408+c];
    #pragma unroll
    for (int reg = 0; reg < 4; ++reg) {
      int r = row0 + quad * 4 + reg;
      if (r < M) {
        float4 cv = cn[reg];
        float irb = cv.x * bcr0 + cv.y * bcr1 + cv.z * bcr2 + cv.w * bcr3;
        float izb = cv.x * bcz0 + cv.y * bcz1 + cv.z * bcz2 + cv.w * bcz3;
        float inb = cv.x * bcn0 + cv.y * bcn1 + cv.z * bcn2 + cv.w * bcn3;
        float rg = sigf(air[reg] + irb + bir + ahr[reg] + bhr);
        float zg = sigf(aiz[reg] + izb + biz + ahz[reg] + bhz);
        float ng = tanhf_fast(ain[reg] + inb + bin_ + rg * (ahn[reg] + bhn));
        float hold = bf2f(hb[(size_t)r * 128 + c]);
        hb[(size_t)r * 128 + c] = f2bf((1.f - zg) * ng + zg * hold);
      }
    }
  }
}

// ---------- fc GEMM (256 cols) fused normalize+sigmoid + el/er; zq out is fp8 ----------
__global__ __launch_bounds__(256) void k_fc_eler(const short* __restrict__ Ab,
    const short* __restrict__ Bp, const float* __restrict__ attn_l,
    const float* __restrict__ attn_r, unsigned char* __restrict__ zq,
    float* __restrict__ el, float* __restrict__ er, int M) {
  int tid = threadIdx.x;
  int lane = tid & 63, wave = tid >> 6;
  int row0 = blockIdx.x * 128 + wave * 32;
  int quad = lane >> 4, l15 = lane & 15;
  short8 af[2][4];
  #pragma unroll
  for (int rt = 0; rt < 2; ++rt) {
    int ar = row0 + rt * 16 + l15; if (ar >= M) ar = M - 1;
    #pragma unroll
    for (int kt = 0; kt < 4; ++kt)
      af[rt][kt] = *(const short8*)(Ab + (size_t)ar * 128 + kt * 32 + quad * 8);
  }
  #pragma unroll
  for (int rt = 0; rt < 2; ++rt) {
    float ss = 0.f;
    #pragma unroll
    for (int kt = 0; kt < 4; ++kt)
      #pragma unroll
      for (int j = 0; j < 8; ++j) {
        float x = bf2f(af[rt][kt][j]);
        ss += x * x;
      }
    ss += __shfl_xor(ss, 16);
    ss += __shfl_xor(ss, 32);
    float inv = 1.f / fmaxf(sqrtf(ss), 1e-12f);
    #pragma unroll
    for (int kt = 0; kt < 4; ++kt)
      #pragma unroll
      for (int j = 0; j < 8; ++j)
        af[rt][kt][j] = f2bf(sigf(bf2f(af[rt][kt][j]) * inv));
  }
  float elp[2][2][4] = {};
  float erp[2][2][4] = {};
  for (int nt = 0; nt < 16; ++nt) {
    f32x4 a0 = {0.f,0.f,0.f,0.f}, a1 = {0.f,0.f,0.f,0.f};
    #pragma unroll
    for (int kt = 0; kt < 4; ++kt) {
      short8 b = *(const short8*)(Bp + (((size_t)(nt * 4 + kt) * 64) + lane) * 8);
      a0 = __builtin_amdgcn_mfma_f32_16x16x32_bf16(af[0][kt], b, a0, 0, 0, 0);
      a1 = __builtin_amdgcn_mfma_f32_16x16x32_bf16(af[1][kt], b, a1, 0, 0, 0);
    }
    int head = nt >> 3;
    int colh = (nt & 7) * 16 + l15;
    float alv = attn_l[head * 128 + colh];
    float arv = attn_r[head * 128 + colh];
    int c = nt * 16 + l15;
    #pragma unroll
    for (int rt = 0; rt < 2; ++rt) {
      f32x4 acc = rt ? a1 : a0;
      #pragma unroll
      for (int reg = 0; reg < 4; ++reg) {
        int r = row0 + rt * 16 + quad * 4 + reg;
        if (r < M) zq[(size_t)r * 256 + c] = f2fp8(acc[reg]);
        elp[rt][head][reg] += acc[reg] * alv;
        erp[rt][head][reg] += acc[reg] * arv;
      }
    }
  }
  #pragma unroll
  for (int off = 1; off < 16; off <<= 1) {
    #pragma unroll
    for (int rt = 0; rt < 2; ++rt)
      #pragma unroll
      for (int h = 0; h < 2; ++h)
        #pragma unroll
        for (int reg = 0; reg < 4; ++reg) {
          elp[rt][h][reg] += __shfl_xor(elp[rt][h][reg], off);
          erp[rt][h][reg] += __shfl_xor(erp[rt][h][reg], off);
        }
  }
  if (l15 == 0) {
    #pragma unroll
    for (int rt = 0; rt < 2; ++rt)
      #pragma unroll
      for (int h = 0; h < 2; ++h)
        #pragma unroll
        for (int reg = 0; reg < 4; ++reg) {
          int r = row0 + rt * 16 + quad * 4 + reg;
          if (r < M) {
            el[r * 2 + h] = elp[rt][h][reg];
            er[r * 2 + h] = erp[rt][h][reg];
          }
        }
  }
}

// ---------- GAT aggregation (online softmax, fp8 gather, readlane + 4x MLP) ----------
__global__ __launch_bounds__(256) void k_gat(const unsigned char* __restrict__ zq,
    const float* __restrict__ el, const float* __restrict__ er,
    const int* __restrict__ row_ofs, const int* __restrict__ csr_se,
    const float* __restrict__ gat_bias, short* __restrict__ outb, int N) {
  int node = blockIdx.x * 4 + (threadIdx.x >> 6);
  int lane = threadIdx.x & 63;
  if (node >= N) return;
  int beg = row_ofs[node], end = row_ofs[node + 1];
  float2 ern = ((const float2*)er)[node];
  float m0 = -INFINITY, m1 = -INFINITY, l0 = 0.f, l1 = 0.f;
  float4 acc = {0.f, 0.f, 0.f, 0.f};
  int head = lane >> 5;
  for (int base = beg; base < end; base += 64) {
    int nv = end - base; if (nv > 64) nv = 64;
    int sidx = (lane < nv) ? (csr_se[base + lane] >> 2) : 0;
    float e0 = -INFINITY, e1 = -INFINITY;
    if (lane < nv) {
      float2 els = ((const float2*)el)[sidx];
      e0 = lrelu(els.x + ern.x);
      e1 = lrelu(els.y + ern.y);
    }
    float c0 = e0, c1 = e1;
    #pragma unroll
    for (int off = 32; off; off >>= 1) {
      c0 = fmaxf(c0, __shfl_xor(c0, off));
      c1 = fmaxf(c1, __shfl_xor(c1, off));
    }
    float nm0 = fmaxf(m0, c0), nm1 = fmaxf(m1, c1);
    float s0 = __expf(m0 - nm0), s1 = __expf(m1 - nm1);
    float p0 = (lane < nv) ? __expf(e0 - nm0) : 0.f;
    float p1 = (lane < nv) ? __expf(e1 - nm1) : 0.f;
    float t0 = p0, t1 = p1;
    #pragma unroll
    for (int off = 32; off; off >>= 1) { t0 += __shfl_xor(t0, off); t1 += __shfl_xor(t1, off); }
    float sc = head ? s1 : s0;
    acc.x *= sc; acc.y *= sc; acc.z *= sc; acc.w *= sc;
    l0 = l0 * s0 + t0; l1 = l1 * s1 + t1;
    m0 = nm0; m1 = nm1;
    unsigned p0u = __float_as_uint(p0), p1u = __float_as_uint(p1);
    int j = 0;
    #define WSEL(J) __uint_as_float(head ? __builtin_amdgcn_readlane(p1u, J) \
                                         : __builtin_amdgcn_readlane(p0u, J))
    #define DECACC(Z, W) do { \
      f32x2 lo_ = __builtin_amdgcn_cvt_pk_f32_fp8(Z, false); \
      f32x2 hi_ = __builtin_amdgcn_cvt_pk_f32_fp8(Z, true); \
      acc.x += W * lo_[0]; acc.y += W * lo_[1]; \
      acc.z += W * hi_[0]; acc.w += W * hi_[1]; } while (0)
    for (; j + 4 <= nv; j += 4) {
      int s0i = __builtin_amdgcn_readlane(sidx, j + 0);
      int s1i = __builtin_amdgcn_readlane(sidx, j + 1);
      int s2i = __builtin_amdgcn_readlane(sidx, j + 2);
      int s3i = __builtin_amdgcn_readlane(sidx, j + 3);
      unsigned z0 = ((const unsigned*)(zq + (size_t)s0i * 256))[lane];
      unsigned z1 = ((const unsigned*)(zq + (size_t)s1i * 256))[lane];
      unsigned z2 = ((const unsigned*)(zq + (size_t)s2i * 256))[lane];
      unsigned z3 = ((const unsigned*)(zq + (size_t)s3i * 256))[lane];
      DECACC(z0, WSEL(j + 0)); DECACC(z1, WSEL(j + 1));
      DECACC(z2, WSEL(j + 2)); DECACC(z3, WSEL(j + 3));
    }
    for (; j < nv; ++j) {
      int sj = __builtin_amdgcn_readlane(sidx, j);
      unsigned zv = ((const unsigned*)(zq + (size_t)sj * 256))[lane];
      DECACC(zv, WSEL(j));
    }
    #undef DECACC
    #undef WSEL
  }
  float inv0 = (l0 > 0.f) ? __fdividef(1.f, l0) : 0.f;
  float inv1 = (l1 > 0.f) ? __fdividef(1.f, l1) : 0.f;
  float inv = head ? inv1 : inv0;
  float4 b = ((const float4*)gat_bias)[lane];
  float ox = fmaxf(acc.x * inv + b.x, 0.f);
  float oy = fmaxf(acc.y * inv + b.y, 0.f);
  float oz = fmaxf(acc.z * inv + b.z, 0.f);
  float ow = fmaxf(acc.w * inv + b.w, 0.f);
  ((uint2*)(outb + (size_t)node * 256))[lane] = make_uint2(pk2(ox, oy), pk2(oz, ow));
}

// ---------- parallel segmented per-graph sums (bf16 input) ----------
__global__ __launch_bounds__(256) void k_segred(const short* __restrict__ hgatb,
    const int* __restrict__ gidc, float* __restrict__ sums, int NT2) {
  int node0 = blockIdx.x * 128;
  int col = threadIdx.x;
  int end = node0 + 128; if (end > NT2) end = NT2;
  if (node0 >= NT2) return;
  float acc = 0.f;
  int gcur = gidc[node0];
  for (int n = node0; n < end; ++n) {
    int g = gidc[n];
    if (g != gcur) {
      atomicAdd(&sums[gcur * 256 + col], acc);
      acc = 0.f; gcur = g;
    }
    acc += bf2f(hgatb[(size_t)n * 256 + col]);
  }
  atomicAdd(&sums[gcur * 256 + col], acc);
}

// ---------- mean + classifier ----------
__global__ __launch_bounds__(64) void k_classify(const float* __restrict__ sums,
    const int* __restrict__ gcnt, const float* __restrict__ W_cls,
    const float* __restrict__ b_cls, float* __restrict__ logits) {
  int g = blockIdx.x, tid = threadIdx.x;
  int hh = tid >> 5, c = tid & 31;
  float invc = 1.f / fmaxf((float)gcnt[g], 1.f);
  float acc = 0.f;
  for (int d = 0; d < D; ++d)
    acc += (sums[g * 256 + hh * D + d] * invc) * W_cls[c * D + d];
  logits[g * 64 + hh * 32 + c] = acc + b_cls[c];
}

// ---------- pairwise distance + softmax over heads (graph g vs g+64) ----------
__global__ __launch_bounds__(64) void k_final(const float* __restrict__ logits,
    float* __restrict__ out) {
  int g = threadIdx.x;
  if (g >= NG) return;
  float d[2];
  #pragma unroll
  for (int hh = 0; hh < 2; ++hh) {
    float s = 0.f;
    for (int c = 0; c < 32; ++c) {
      float df = logits[g * 64 + hh * 32 + c] - logits[(g + NG) * 64 + hh * 32 + c] + 1e-6f;
      s += df * df;
    }
    d[hh] = sqrtf(s);
  }
  float mx = fmaxf(d[0], d[1]);
  float e0 = expf(d[0] - mx), e1 = expf(d[1] - mx);
  float den = e0 + e1;
  out[g * 2] = e0 / den;
  out[g * 2 + 1] = e1 / den;
}

extern "C" void kernel_launch(void* const* d_in, const int* in_sizes, int n_in,
                              void* d_out, int out_size, void* d_ws, size_t ws_size,
                              hipStream_t stream) {
  const float* in_feat1 = (const float*)d_in[0];
  const float* in_feat2 = (const float*)d_in[1];
  const int* src1 = (const int*)d_in[2];
  const int* dst1 = (const int*)d_in[3];
  const int* ety1 = (const int*)d_in[4];
  const int* gid1 = (const int*)d_in[5];
  const int* src2 = (const int*)d_in[6];
  const int* dst2 = (const int*)d_in[7];
  const int* ety2 = (const int*)d_in[8];
  const int* gid2 = (const int*)d_in[9];
  const float* W_et = (const float*)d_in[10];
  const float* b_et = (const float*)d_in[11];
  const float* W_ih = (const float*)d_in[12];
  const float* W_hh = (const float*)d_in[13];
  const float* b_ih = (const float*)d_in[14];
  const float* b_hh = (const float*)d_in[15];
  const float* W_fc = (const float*)d_in[16];
  const float* attn_l = (const float*)d_in[17];
  const float* attn_r = (const float*)d_in[18];
  const float* gat_bias = (const float*)d_in[19];
  const float* W_cls = (const float*)d_in[20];
  const float* b_cls = (const float*)d_in[21];
  float* out = (float*)d_out;

  int N = in_sizes[0] / D;
  int E = in_sizes[2];
  int N2 = 2 * N, E2 = 2 * E;

  char* p = (char*)d_ws;
  auto alloc = [&](size_t bytes) -> void* {
    char* r = p;
    p += (bytes + 255) & ~(size_t)255;
    return (void*)r;
  };
  short* WcombP = (short*)alloc((size_t)384 * 512 * 2);  // fused W_ih·W_et, K=512 frags
  short* WhhP = (short*)alloc((size_t)384 * 128 * 2);
  short* WfcP = (short*)alloc((size_t)256 * 128 * 2);
  float* Bc   = (float*)alloc((size_t)4 * 384 * 4);      // W_ih·b_et
  short* hb  = (short*)alloc((size_t)N2 * D * 2);
  short* S   = (short*)alloc((size_t)N2 * 512 * 2);      // per-etype h sums; hgatb overlays
  unsigned char* zq = (unsigned char*)alloc((size_t)N2 * 256); // fp8 zft
  float* el  = (float*)alloc((size_t)N2 * 2 * 4);
  float* er  = (float*)alloc((size_t)N2 * 2 * 4);
  float* cntf= (float*)alloc((size_t)N2 * 4 * 4);
  float* sums= (float*)alloc((size_t)NG2 * 256 * 4);
  float* logits = (float*)alloc((size_t)NG2 * 64 * 4);
  int* deg     = (int*)alloc((size_t)N2 * 4);
  int* row_ofs = (int*)alloc(((size_t)N2 + 1) * 4);
  int* cursor  = (int*)alloc((size_t)N2 * 4);
  int* gidc    = (int*)alloc((size_t)N2 * 4);
  int* gcnt    = (int*)alloc((size_t)NG2 * 4);
  int* bsum    = (int*)alloc((size_t)1024 * 4);
  int* boffs   = (int*)alloc((size_t)1024 * 4);
  int* csr_se  = (int*)alloc((size_t)E2 * 4);
  if ((size_t)(p - (char*)d_ws) > ws_size) return;

  short* hgatb = S;   // [N2,256] bf16 — overlays S (dead after last k_gru2)

  // weight precompute/packing
  k_packComb<<<dim3(256), dim3(256), 0, stream>>>(W_ih, W_et, WcombP);
  k_bc<<<dim3(6), dim3(256), 0, stream>>>(W_ih, b_et, Bc);
  k_pack<<<dim3(48), dim3(256), 0, stream>>>(W_hh, WhhP, 384);
  k_pack<<<dim3(32), dim3(256), 0, stream>>>(W_fc, WfcP, 256);

  // CSR for merged graph
  hipMemsetAsync(deg, 0, (size_t)N2 * 4, stream);
  hipMemsetAsync(gcnt, 0, (size_t)NG2 * 4, stream);
  int eb = (E2 + 255) / 256;
  int nb = (N2 + 1023) / 1024;
  k_hist<<<dim3(eb), dim3(256), 0, stream>>>(dst1, dst2, E, N, deg);
  k_scan_a<<<dim3(nb), dim3(256), 0, stream>>>(deg, N2, bsum);
  k_scan_b<<<dim3(1), dim3(1024), 0, stream>>>(bsum, boffs, nb);
  k_scan_c<<<dim3(nb), dim3(256), 0, stream>>>(deg, boffs, row_ofs, cursor, N2);
  k_scatter<<<dim3(eb), dim3(256), 0, stream>>>(src1, dst1, ety1, src2, dst2, ety2,
                                                E, N, cursor, csr_se);
  k_fillgid<<<dim3((N2 + 255) / 256), dim3(256), 0, stream>>>(gid1, gid2, N, gidc, gcnt);

  // init h (bf16)
  k_init<<<dim3(1024), dim3(256), 0, stream>>>(in_feat1, in_feat2, hb, N * D / 4);

  int gb64 = (N2 + 63) / 64;
  int gb128 = (N2 + 127) / 128;
  int nb4 = (N2 + 3) / 4;

  for (int s = 0; s < NSTEPS; ++s) {
    k_aggS<<<dim3(nb4), dim3(256), 0, stream>>>(hb, row_ofs, csr_se, S, cntf, N2);
    k_gru2<<<dim3(gb64), dim3(256), 0, stream>>>(S, hb, cntf, WcombP, WhhP,
                                                 Bc, b_ih, b_hh, N2);
  }
  k_fc_eler<<<dim3(gb128), dim3(256), 0, stream>>>(hb, WfcP, attn_l, attn_r, zq, el, er, N2);
  k_gat<<<dim3(nb4), dim3(256), 0, stream>>>(zq, el, er, row_ofs, csr_se,
                                             gat_bias, hgatb, N2);
  hipMemsetAsync(sums, 0, (size_t)NG2 * 256 * 4, stream);
  k_segred<<<dim3((N2 + 127) / 128), dim3(256), 0, stream>>>(hgatb, gidc, sums, N2);
  k_classify<<<dim3(NG2), dim3(64), 0, stream>>>(sums, gcnt, W_cls, b_cls, logits);
  k_final<<<dim3(1), dim3(64), 0, stream>>>(logits, out);
}

// Round 13
// 1341.975 us; speedup vs baseline: 1.2036x; 1.2036x over previous
//
#include <hip/hip_runtime.h>
#include <math.h>

#define D 128
#define NG 64
#define NG2 128
#define NSTEPS 5

using short8 = __attribute__((ext_vector_type(8))) short;
using f32x4  = __attribute__((ext_vector_type(4))) float;
using f32x2  = __attribute__((ext_vector_type(2))) float;

// fast, overflow-safe transcendentals (v_exp_f32 + v_rcp_f32)
__device__ __forceinline__ float sigf(float x) {
  float e = __expf(-fabsf(x));
  float inv = __fdividef(1.f, 1.f + e);
  return x >= 0.f ? inv : e * inv;
}
__device__ __forceinline__ float tanhf_fast(float x) {
  float e = __expf(-2.f * fabsf(x));
  float r = (1.f - e) * __fdividef(1.f, 1.f + e);
  return x >= 0.f ? r : -r;
}
__device__ __forceinline__ float lrelu(float x) { return x > 0.f ? x : 0.2f * x; }
__device__ __forceinline__ short f2bf(float x) {
  unsigned u = __float_as_uint(x);
  u += 0x7fff + ((u >> 16) & 1);
  return (short)(u >> 16);
}
__device__ __forceinline__ unsigned pk2(float x, float y) {
  return ((unsigned)(unsigned short)f2bf(y) << 16) | (unsigned short)f2bf(x);
}
__device__ __forceinline__ float bflo(unsigned v) { return __uint_as_float(v << 16); }
__device__ __forceinline__ float bfhi(unsigned v) { return __uint_as_float(v & 0xffff0000u); }
__device__ __forceinline__ float bf2f(short s) {
  return __uint_as_float(((unsigned)(unsigned short)s) << 16);
}
__device__ __forceinline__ unsigned char f2fp8(float x) {
  int p = __builtin_amdgcn_cvt_pk_fp8_f32(x, x, 0, false);
  return (unsigned char)(p & 0xff);
}

// ---------- init: concat(in_feat1,in_feat2) -> hb (bf16) ----------
__global__ void k_init(const float* __restrict__ f1, const float* __restrict__ f2,
                       short* __restrict__ hb, int Nd4) {
  int tot = 2 * Nd4;
  for (int i = blockIdx.x * blockDim.x + threadIdx.x; i < tot; i += gridDim.x * blockDim.x) {
    float4 v = (i < Nd4) ? ((const float4*)f1)[i] : ((const float4*)f2)[i - Nd4];
    ((uint2*)hb)[i] = make_uint2(pk2(v.x, v.y), pk2(v.z, v.w));
  }
}

// ---------- pack W[NC][128] into MFMA b-frag order, K=128 ----------
__global__ void k_pack(const float* __restrict__ W, short* __restrict__ P, int NC) {
  int n = NC * 128;
  for (int i = blockIdx.x * blockDim.x + threadIdx.x; i < n; i += gridDim.x * blockDim.x) {
    int j = i & 7;
    int lane = (i >> 3) & 63;
    int kt = (i >> 9) & 3;
    int nt = i >> 11;
    int c = nt * 16 + (lane & 15);
    int k = kt * 32 + ((lane >> 4) << 3) + j;
    P[i] = f2bf(W[c * 128 + k]);
  }
}

// ---------- pack stacked W_et [4][128 out][128 in] as B[K=512][out=128] frags ----------
__global__ void k_packA512(const float* __restrict__ W_et, short* __restrict__ P) {
  int n = 128 * 512;
  for (int i = blockIdx.x * blockDim.x + threadIdx.x; i < n; i += gridDim.x * blockDim.x) {
    int j = i & 7;
    int lane = (i >> 3) & 63;
    int kt = (i >> 9) & 15;
    int nt = i >> 13;
    int c = nt * 16 + (lane & 15);
    int k = kt * 32 + ((lane >> 4) << 3) + j;
    P[i] = f2bf(W_et[(k >> 7) * 16384 + c * 128 + (k & 127)]);
  }
}

// ---------- CSR build over merged graph ----------
__global__ void k_hist(const int* __restrict__ dst1, const int* __restrict__ dst2,
                       int E, int N, int* __restrict__ deg) {
  for (int e = blockIdx.x * blockDim.x + threadIdx.x; e < 2 * E; e += gridDim.x * blockDim.x) {
    int d = (e < E) ? dst1[e] : dst2[e - E] + N;
    atomicAdd(&deg[d], 1);
  }
}

__global__ __launch_bounds__(256) void k_scan_a(const int* __restrict__ deg, int n,
                                                int* __restrict__ bsum) {
  int base = blockIdx.x * 1024 + threadIdx.x * 4;
  int s = 0;
  if (base + 3 < n) {
    int4 v = *(const int4*)(deg + base);
    s = v.x + v.y + v.z + v.w;
  } else {
    for (int k = 0; k < 4; ++k) if (base + k < n) s += deg[base + k];
  }
  #pragma unroll
  for (int off = 32; off; off >>= 1) s += __shfl_xor(s, off);
  __shared__ int ws[4];
  if ((threadIdx.x & 63) == 0) ws[threadIdx.x >> 6] = s;
  __syncthreads();
  if (threadIdx.x == 0) bsum[blockIdx.x] = ws[0] + ws[1] + ws[2] + ws[3];
}

__global__ __launch_bounds__(1024) void k_scan_b(const int* __restrict__ bsum,
                                                 int* __restrict__ boffs, int nb) {
  int tid = threadIdx.x;
  int v = (tid < nb) ? bsum[tid] : 0;
  int lane = tid & 63, wv = tid >> 6;
  int x = v;
  #pragma unroll
  for (int off = 1; off < 64; off <<= 1) {
    int y = __shfl_up(x, off);
    if (lane >= off) x += y;
  }
  __shared__ int wsum[16];
  if (lane == 63) wsum[wv] = x;
  __syncthreads();
  if (tid < 16) {
    int u = wsum[tid];
    #pragma unroll
    for (int off = 1; off < 16; off <<= 1) {
      int y = __shfl_up(u, off);
      if (tid >= off) u += y;
    }
    wsum[tid] = u;
  }
  __syncthreads();
  int woff = wv ? wsum[wv - 1] : 0;
  if (tid < nb) boffs[tid] = woff + x - v;
}

__global__ __launch_bounds__(256) void k_scan_c(const int* __restrict__ deg,
    const int* __restrict__ boffs, int* __restrict__ row_ofs,
    int* __restrict__ cursor, int n) {
  int base = blockIdx.x * 1024 + threadIdx.x * 4;
  int v[4] = {0, 0, 0, 0};
  if (base + 3 < n) {
    int4 t = *(const int4*)(deg + base);
    v[0] = t.x; v[1] = t.y; v[2] = t.z; v[3] = t.w;
  } else {
    for (int k = 0; k < 4; ++k) if (base + k < n) v[k] = deg[base + k];
  }
  int s = v[0] + v[1] + v[2] + v[3];
  int lane = threadIdx.x & 63, wv = threadIdx.x >> 6;
  int x = s;
  #pragma unroll
  for (int off = 1; off < 64; off <<= 1) {
    int y = __shfl_up(x, off);
    if (lane >= off) x += y;
  }
  __shared__ int wsum[4];
  if (lane == 63) wsum[wv] = x;
  __syncthreads();
  int woff = 0;
  for (int w = 0; w < wv; ++w) woff += wsum[w];
  int run = boffs[blockIdx.x] + woff + x - s;
  #pragma unroll
  for (int k = 0; k < 4; ++k) {
    int i = base + k;
    if (i < n) {
      cursor[i] = run;
      run += v[k];
      row_ofs[i + 1] = run;
    }
  }
  if (blockIdx.x == 0 && threadIdx.x == 0) row_ofs[0] = 0;
}

// scatter: single merged array csr_se = src*4 + etype
__global__ void k_scatter(const int* __restrict__ src1, const int* __restrict__ dst1,
                          const int* __restrict__ ety1, const int* __restrict__ src2,
                          const int* __restrict__ dst2, const int* __restrict__ ety2,
                          int E, int N, int* __restrict__ cursor,
                          int* __restrict__ csr_se) {
  for (int e = blockIdx.x * blockDim.x + threadIdx.x; e < 2 * E; e += gridDim.x * blockDim.x) {
    int s, d, et;
    if (e < E) { s = src1[e]; d = dst1[e]; et = ety1[e]; }
    else { s = src2[e - E] + N; d = dst2[e - E] + N; et = ety2[e - E]; }
    int p = atomicAdd(&cursor[d], 1);
    csr_se[p] = s * 4 + et;
  }
}

// ---------- merged gid array [2N] + per-graph counts [128] ----------
__global__ void k_fillgid(const int* __restrict__ gid1, const int* __restrict__ gid2,
                          int N, int* __restrict__ gidc, int* __restrict__ gcnt) {
  __shared__ int cnt[NG2];
  int t = threadIdx.x;
  if (t < NG2) cnt[t] = 0;
  __syncthreads();
  int i = blockIdx.x * 256 + t;
  if (i < 2 * N) {
    int g = (i < N) ? gid1[i] : gid2[i - N] + NG;
    gidc[i] = g;
    atomicAdd(&cnt[g], 1);
  }
  __syncthreads();
  if (t < NG2 && cnt[t]) atomicAdd(&gcnt[t], cnt[t]);
}

// ---------- per-etype neighbor sums + counts; readlane, 8x + 4x + 1x MLP tiers ----------
__global__ __launch_bounds__(256) void k_aggS(const short* __restrict__ hb,
    const int* __restrict__ row_ofs, const int* __restrict__ csr_se,
    short* __restrict__ S, float* __restrict__ cntf, int N) {
  int node = blockIdx.x * 4 + (threadIdx.x >> 6);
  int lane = threadIdx.x & 63;
  if (node >= N) return;
  int beg = row_ofs[node], end = row_ofs[node + 1];
  float a0x = 0.f, a0y = 0.f, a1x = 0.f, a1y = 0.f;
  float a2x = 0.f, a2y = 0.f, a3x = 0.f, a3y = 0.f;
  int c0 = 0, c1 = 0, c2 = 0, c3 = 0;
  #define ACC(ET, VX, VY) do { \
      if (ET == 0)      { a0x += VX; a0y += VY; ++c0; } \
      else if (ET == 1) { a1x += VX; a1y += VY; ++c1; } \
      else if (ET == 2) { a2x += VX; a2y += VY; ++c2; } \
      else              { a3x += VX; a3y += VY; ++c3; } } while (0)
  for (int base = beg; base < end; base += 64) {
    int nv = end - base; if (nv > 64) nv = 64;
    int r = (lane < nv) ? csr_se[base + lane] : 0;
    int j = 0;
    for (; j + 8 <= nv; j += 8) {
      int rr0 = __builtin_amdgcn_readlane(r, j + 0);
      int rr1 = __builtin_amdgcn_readlane(r, j + 1);
      int rr2 = __builtin_amdgcn_readlane(r, j + 2);
      int rr3 = __builtin_amdgcn_readlane(r, j + 3);
      int rr4 = __builtin_amdgcn_readlane(r, j + 4);
      int rr5 = __builtin_amdgcn_readlane(r, j + 5);
      int rr6 = __builtin_amdgcn_readlane(r, j + 6);
      int rr7 = __builtin_amdgcn_readlane(r, j + 7);
      unsigned v0 = ((const unsigned*)(hb + (size_t)(rr0 >> 2) * 128))[lane];
      unsigned v1 = ((const unsigned*)(hb + (size_t)(rr1 >> 2) * 128))[lane];
      unsigned v2 = ((const unsigned*)(hb + (size_t)(rr2 >> 2) * 128))[lane];
      unsigned v3 = ((const unsigned*)(hb + (size_t)(rr3 >> 2) * 128))[lane];
      unsigned v4 = ((const unsigned*)(hb + (size_t)(rr4 >> 2) * 128))[lane];
      unsigned v5 = ((const unsigned*)(hb + (size_t)(rr5 >> 2) * 128))[lane];
      unsigned v6 = ((const unsigned*)(hb + (size_t)(rr6 >> 2) * 128))[lane];
      unsigned v7 = ((const unsigned*)(hb + (size_t)(rr7 >> 2) * 128))[lane];
      ACC(rr0 & 3, bflo(v0), bfhi(v0));
      ACC(rr1 & 3, bflo(v1), bfhi(v1));
      ACC(rr2 & 3, bflo(v2), bfhi(v2));
      ACC(rr3 & 3, bflo(v3), bfhi(v3));
      ACC(rr4 & 3, bflo(v4), bfhi(v4));
      ACC(rr5 & 3, bflo(v5), bfhi(v5));
      ACC(rr6 & 3, bflo(v6), bfhi(v6));
      ACC(rr7 & 3, bflo(v7), bfhi(v7));
    }
    // 4-wide mid tier: kills the serial-tail latency for avg-degree ~12 rows
    for (; j + 4 <= nv; j += 4) {
      int rr0 = __builtin_amdgcn_readlane(r, j + 0);
      int rr1 = __builtin_amdgcn_readlane(r, j + 1);
      int rr2 = __builtin_amdgcn_readlane(r, j + 2);
      int rr3 = __builtin_amdgcn_readlane(r, j + 3);
      unsigned v0 = ((const unsigned*)(hb + (size_t)(rr0 >> 2) * 128))[lane];
      unsigned v1 = ((const unsigned*)(hb + (size_t)(rr1 >> 2) * 128))[lane];
      unsigned v2 = ((const unsigned*)(hb + (size_t)(rr2 >> 2) * 128))[lane];
      unsigned v3 = ((const unsigned*)(hb + (size_t)(rr3 >> 2) * 128))[lane];
      ACC(rr0 & 3, bflo(v0), bfhi(v0));
      ACC(rr1 & 3, bflo(v1), bfhi(v1));
      ACC(rr2 & 3, bflo(v2), bfhi(v2));
      ACC(rr3 & 3, bflo(v3), bfhi(v3));
    }
    for (; j < nv; ++j) {
      int rr = __builtin_amdgcn_readlane(r, j);
      unsigned v = ((const unsigned*)(hb + (size_t)(rr >> 2) * 128))[lane];
      ACC(rr & 3, bflo(v), bfhi(v));
    }
  }
  #undef ACC
  size_t b = (size_t)node * 512;
  ((unsigned*)(S + b      ))[lane] = pk2(a0x, a0y);
  ((unsigned*)(S + b + 128))[lane] = pk2(a1x, a1y);
  ((unsigned*)(S + b + 256))[lane] = pk2(a2x, a2y);
  ((unsigned*)(S + b + 384))[lane] = pk2(a3x, a3y);
  if (lane == 0) {
    float4 cv = {(float)c0, (float)c1, (float)c2, (float)c3};
    *(float4*)(cntf + (size_t)node * 4) = cv;
  }
}

// ---------- a = S[M,512] @ Wa (K=512 MFMA) + cnt_et·b_et  -> ab (bf16) ----------
__global__ __launch_bounds__(256) void k_agemm(const short* __restrict__ S,
    const short* __restrict__ WaP, const float* __restrict__ b_et,
    const float* __restrict__ cntf, short* __restrict__ ab, int M) {
  int tid = threadIdx.x;
  int lane = tid & 63, wave = tid >> 6;
  int row0 = blockIdx.x * 64 + wave * 16;
  int quad = lane >> 4, l15 = lane & 15;
  int ar = row0 + l15; if (ar >= M) ar = M - 1;
  short8 sf[16];
  #pragma unroll
  for (int kt = 0; kt < 16; ++kt)
    sf[kt] = *(const short8*)(S + (size_t)ar * 512 + kt * 32 + quad * 8);
  float4 cn[4];
  #pragma unroll
  for (int reg = 0; reg < 4; ++reg) {
    int r = row0 + quad * 4 + reg; if (r >= M) r = M - 1;
    cn[reg] = *(const float4*)(cntf + (size_t)r * 4);
  }
  for (int nt = 0; nt < 8; ++nt) {
    f32x4 acc = {0.f, 0.f, 0.f, 0.f};
    #pragma unroll
    for (int kt = 0; kt < 16; ++kt) {
      short8 b = *(const short8*)(WaP + (((size_t)(nt * 16 + kt) * 64) + lane) * 8);
      acc = __builtin_amdgcn_mfma_f32_16x16x32_bf16(sf[kt], b, acc, 0, 0, 0);
    }
    int c = nt * 16 + l15;
    float be0 = b_et[c], be1 = b_et[128 + c], be2 = b_et[256 + c], be3 = b_et[384 + c];
    #pragma unroll
    for (int reg = 0; reg < 4; ++reg) {
      int r = row0 + quad * 4 + reg;
      if (r < M) {
        float v = acc[reg] + cn[reg].x * be0 + cn[reg].y * be1
                           + cn[reg].z * be2 + cn[reg].w * be3;
        ab[(size_t)r * 128 + c] = f2bf(v);
      }
    }
  }
}

// ---------- fused GRU via MFMA, 32 rows/wave, bf16 recurrent state ----------
__global__ __launch_bounds__(256) void k_gru_mfma(const short* __restrict__ ab,
    short* __restrict__ hb,
    const short* __restrict__ Pih, const short* __restrict__ Phh,
    const float* __restrict__ b_ih, const float* __restrict__ b_hh, int M) {
  int tid = threadIdx.x;
  int lane = tid & 63, wave = tid >> 6;
  int row0 = blockIdx.x * 128 + wave * 32;
  int quad = lane >> 4, l15 = lane & 15;
  short8 fa[2][4], fh[2][4];
  #pragma unroll
  for (int rt = 0; rt < 2; ++rt) {
    int ar = row0 + rt * 16 + l15; if (ar >= M) ar = M - 1;
    #pragma unroll
    for (int kt = 0; kt < 4; ++kt) {
      fa[rt][kt] = *(const short8*)(ab + (size_t)ar * 128 + kt * 32 + quad * 8);
      fh[rt][kt] = *(const short8*)(hb + (size_t)ar * 128 + kt * 32 + quad * 8);
    }
  }
  for (int nt = 0; nt < 8; ++nt) {
    f32x4 accr[2], accz[2], acci[2], acch[2];
    #pragma unroll
    for (int rt = 0; rt < 2; ++rt) {
      accr[rt] = {0.f,0.f,0.f,0.f}; accz[rt] = {0.f,0.f,0.f,0.f};
      acci[rt] = {0.f,0.f,0.f,0.f}; acch[rt] = {0.f,0.f,0.f,0.f};
    }
    #pragma unroll
    for (int kt = 0; kt < 4; ++kt) {
      size_t li = ((size_t)lane) * 8;
      short8 wr = *(const short8*)(Pih + ((size_t)((nt     ) * 4 + kt) * 64) * 8 + li);
      short8 wz = *(const short8*)(Pih + ((size_t)((nt +  8) * 4 + kt) * 64) * 8 + li);
      short8 wn = *(const short8*)(Pih + ((size_t)((nt + 16) * 4 + kt) * 64) * 8 + li);
      short8 ur = *(const short8*)(Phh + ((size_t)((nt     ) * 4 + kt) * 64) * 8 + li);
      short8 uz = *(const short8*)(Phh + ((size_t)((nt +  8) * 4 + kt) * 64) * 8 + li);
      short8 un = *(const short8*)(Phh + ((size_t)((nt + 16) * 4 + kt) * 64) * 8 + li);
      #pragma unroll
      for (int rt = 0; rt < 2; ++rt) {
        accr[rt] = __builtin_amdgcn_mfma_f32_16x16x32_bf16(fa[rt][kt], wr, accr[rt], 0, 0, 0);
        accr[rt] = __builtin_amdgcn_mfma_f32_16x16x32_bf16(fh[rt][kt], ur, accr[rt], 0, 0, 0);
        accz[rt] = __builtin_amdgcn_mfma_f32_16x16x32_bf16(fa[rt][kt], wz, accz[rt], 0, 0, 0);
        accz[rt] = __builtin_amdgcn_mfma_f32_16x16x32_bf16(fh[rt][kt], uz, accz[rt], 0, 0, 0);
        acci[rt] = __builtin_amdgcn_mfma_f32_16x16x32_bf16(fa[rt][kt], wn, acci[rt], 0, 0, 0);
        acch[rt] = __builtin_amdgcn_mfma_f32_16x16x32_bf16(fh[rt][kt], un, acch[rt], 0, 0, 0);
      }
    }
    int c = nt * 16 + l15;
    float bir = b_ih[c],      bhr = b_hh[c];
    float biz = b_ih[c+128],  bhz = b_hh[c+128];
    float bin_= b_ih[c+256],  bhn = b_hh[c+256];
    #pragma unroll
    for (int rt = 0; rt < 2; ++rt) {
      #pragma unroll
      for (int reg = 0; reg < 4; ++reg) {
        int r = row0 + rt * 16 + quad * 4 + reg;
        if (r < M) {
          float rg = sigf(accr[rt][reg] + bir + bhr);
          float zg = sigf(accz[rt][reg] + biz + bhz);
          float ng = tanhf_fast(acci[rt][reg] + bin_ + rg * (acch[rt][reg] + bhn));
          float hold = bf2f(hb[(size_t)r * 128 + c]);
          float hn2 = (1.f - zg) * ng + zg * hold;
          hb[(size_t)r * 128 + c] = f2bf(hn2);
        }
      }
    }
  }
}

// ---------- fc GEMM (256 cols) fused normalize+sigmoid + el/er; zq out is fp8 ----------
__global__ __launch_bounds__(256) void k_fc_eler(const short* __restrict__ Ab,
    const short* __restrict__ Bp, const float* __restrict__ attn_l,
    const float* __restrict__ attn_r, unsigned char* __restrict__ zq,
    float* __restrict__ el, float* __restrict__ er, int M) {
  int tid = threadIdx.x;
  int lane = tid & 63, wave = tid >> 6;
  int row0 = blockIdx.x * 128 + wave * 32;
  int quad = lane >> 4, l15 = lane & 15;
  short8 af[2][4];
  #pragma unroll
  for (int rt = 0; rt < 2; ++rt) {
    int ar = row0 + rt * 16 + l15; if (ar >= M) ar = M - 1;
    #pragma unroll
    for (int kt = 0; kt < 4; ++kt)
      af[rt][kt] = *(const short8*)(Ab + (size_t)ar * 128 + kt * 32 + quad * 8);
  }
  #pragma unroll
  for (int rt = 0; rt < 2; ++rt) {
    float ss = 0.f;
    #pragma unroll
    for (int kt = 0; kt < 4; ++kt)
      #pragma unroll
      for (int j = 0; j < 8; ++j) {
        float x = bf2f(af[rt][kt][j]);
        ss += x * x;
      }
    ss += __shfl_xor(ss, 16);
    ss += __shfl_xor(ss, 32);
    float inv = 1.f / fmaxf(sqrtf(ss), 1e-12f);
    #pragma unroll
    for (int kt = 0; kt < 4; ++kt)
      #pragma unroll
      for (int j = 0; j < 8; ++j)
        af[rt][kt][j] = f2bf(sigf(bf2f(af[rt][kt][j]) * inv));
  }
  float elp[2][2][4] = {};
  float erp[2][2][4] = {};
  for (int nt = 0; nt < 16; ++nt) {
    f32x4 a0 = {0.f,0.f,0.f,0.f}, a1 = {0.f,0.f,0.f,0.f};
    #pragma unroll
    for (int kt = 0; kt < 4; ++kt) {
      short8 b = *(const short8*)(Bp + (((size_t)(nt * 4 + kt) * 64) + lane) * 8);
      a0 = __builtin_amdgcn_mfma_f32_16x16x32_bf16(af[0][kt], b, a0, 0, 0, 0);
      a1 = __builtin_amdgcn_mfma_f32_16x16x32_bf16(af[1][kt], b, a1, 0, 0, 0);
    }
    int head = nt >> 3;
    int colh = (nt & 7) * 16 + l15;
    float alv = attn_l[head * 128 + colh];
    float arv = attn_r[head * 128 + colh];
    int c = nt * 16 + l15;
    #pragma unroll
    for (int rt = 0; rt < 2; ++rt) {
      f32x4 acc = rt ? a1 : a0;
      #pragma unroll
      for (int reg = 0; reg < 4; ++reg) {
        int r = row0 + rt * 16 + quad * 4 + reg;
        if (r < M) zq[(size_t)r * 256 + c] = f2fp8(acc[reg]);
        elp[rt][head][reg] += acc[reg] * alv;
        erp[rt][head][reg] += acc[reg] * arv;
      }
    }
  }
  #pragma unroll
  for (int off = 1; off < 16; off <<= 1) {
    #pragma unroll
    for (int rt = 0; rt < 2; ++rt)
      #pragma unroll
      for (int h = 0; h < 2; ++h)
        #pragma unroll
        for (int reg = 0; reg < 4; ++reg) {
          elp[rt][h][reg] += __shfl_xor(elp[rt][h][reg], off);
          erp[rt][h][reg] += __shfl_xor(erp[rt][h][reg], off);
        }
  }
  if (l15 == 0) {
    #pragma unroll
    for (int rt = 0; rt < 2; ++rt)
      #pragma unroll
      for (int h = 0; h < 2; ++h)
        #pragma unroll
        for (int reg = 0; reg < 4; ++reg) {
          int r = row0 + rt * 16 + quad * 4 + reg;
          if (r < M) {
            el[r * 2 + h] = elp[rt][h][reg];
            er[r * 2 + h] = erp[rt][h][reg];
          }
        }
  }
}

// ---------- GAT aggregation (online softmax, fp8 gather, readlane + 4x MLP) ----------
// R9-exact: libm expf + plain div keeps VGPR at 24 -> occupancy ~73%
__global__ __launch_bounds__(256) void k_gat(const unsigned char* __restrict__ zq,
    const float* __restrict__ el, const float* __restrict__ er,
    const int* __restrict__ row_ofs, const int* __restrict__ csr_se,
    const float* __restrict__ gat_bias, short* __restrict__ outb, int N) {
  int node = blockIdx.x * 4 + (threadIdx.x >> 6);
  int lane = threadIdx.x & 63;
  if (node >= N) return;
  int beg = row_ofs[node], end = row_ofs[node + 1];
  float2 ern = ((const float2*)er)[node];
  float m0 = -INFINITY, m1 = -INFINITY, l0 = 0.f, l1 = 0.f;
  float4 acc = {0.f, 0.f, 0.f, 0.f};
  int head = lane >> 5;
  for (int base = beg; base < end; base += 64) {
    int nv = end - base; if (nv > 64) nv = 64;
    int sidx = (lane < nv) ? (csr_se[base + lane] >> 2) : 0;
    float e0 = -INFINITY, e1 = -INFINITY;
    if (lane < nv) {
      float2 els = ((const float2*)el)[sidx];
      e0 = lrelu(els.x + ern.x);
      e1 = lrelu(els.y + ern.y);
    }
    float c0 = e0, c1 = e1;
    #pragma unroll
    for (int off = 32; off; off >>= 1) {
      c0 = fmaxf(c0, __shfl_xor(c0, off));
      c1 = fmaxf(c1, __shfl_xor(c1, off));
    }
    float nm0 = fmaxf(m0, c0), nm1 = fmaxf(m1, c1);
    float s0 = expf(m0 - nm0), s1 = expf(m1 - nm1);
    float p0 = (lane < nv) ? expf(e0 - nm0) : 0.f;
    float p1 = (lane < nv) ? expf(e1 - nm1) : 0.f;
    float t0 = p0, t1 = p1;
    #pragma unroll
    for (int off = 32; off; off >>= 1) { t0 += __shfl_xor(t0, off); t1 += __shfl_xor(t1, off); }
    float sc = head ? s1 : s0;
    acc.x *= sc; acc.y *= sc; acc.z *= sc; acc.w *= sc;
    l0 = l0 * s0 + t0; l1 = l1 * s1 + t1;
    m0 = nm0; m1 = nm1;
    unsigned p0u = __float_as_uint(p0), p1u = __float_as_uint(p1);
    int j = 0;
    #define WSEL(J) __uint_as_float(head ? __builtin_amdgcn_readlane(p1u, J) \
                                         : __builtin_amdgcn_readlane(p0u, J))
    #define DECACC(Z, W) do { \
      f32x2 lo_ = __builtin_amdgcn_cvt_pk_f32_fp8(Z, false); \
      f32x2 hi_ = __builtin_amdgcn_cvt_pk_f32_fp8(Z, true); \
      acc.x += W * lo_[0]; acc.y += W * lo_[1]; \
      acc.z += W * hi_[0]; acc.w += W * hi_[1]; } while (0)
    for (; j + 4 <= nv; j += 4) {
      int s0i = __builtin_amdgcn_readlane(sidx, j + 0);
      int s1i = __builtin_amdgcn_readlane(sidx, j + 1);
      int s2i = __builtin_amdgcn_readlane(sidx, j + 2);
      int s3i = __builtin_amdgcn_readlane(sidx, j + 3);
      unsigned z0 = ((const unsigned*)(zq + (size_t)s0i * 256))[lane];
      unsigned z1 = ((const unsigned*)(zq + (size_t)s1i * 256))[lane];
      unsigned z2 = ((const unsigned*)(zq + (size_t)s2i * 256))[lane];
      unsigned z3 = ((const unsigned*)(zq + (size_t)s3i * 256))[lane];
      DECACC(z0, WSEL(j + 0)); DECACC(z1, WSEL(j + 1));
      DECACC(z2, WSEL(j + 2)); DECACC(z3, WSEL(j + 3));
    }
    for (; j < nv; ++j) {
      int sj = __builtin_amdgcn_readlane(sidx, j);
      unsigned zv = ((const unsigned*)(zq + (size_t)sj * 256))[lane];
      DECACC(zv, WSEL(j));
    }
    #undef DECACC
    #undef WSEL
  }
  float inv0 = (l0 > 0.f) ? 1.f / l0 : 0.f;
  float inv1 = (l1 > 0.f) ? 1.f / l1 : 0.f;
  float inv = head ? inv1 : inv0;
  float4 b = ((const float4*)gat_bias)[lane];
  float ox = fmaxf(acc.x * inv + b.x, 0.f);
  float oy = fmaxf(acc.y * inv + b.y, 0.f);
  float oz = fmaxf(acc.z * inv + b.z, 0.f);
  float ow = fmaxf(acc.w * inv + b.w, 0.f);
  ((uint2*)(outb + (size_t)node * 256))[lane] = make_uint2(pk2(ox, oy), pk2(oz, ow));
}

// ---------- parallel segmented per-graph sums (bf16 input) ----------
__global__ __launch_bounds__(256) void k_segred(const short* __restrict__ hgatb,
    const int* __restrict__ gidc, float* __restrict__ sums, int NT2) {
  int node0 = blockIdx.x * 128;
  int col = threadIdx.x;
  int end = node0 + 128; if (end > NT2) end = NT2;
  if (node0 >= NT2) return;
  float acc = 0.f;
  int gcur = gidc[node0];
  for (int n = node0; n < end; ++n) {
    int g = gidc[n];
    if (g != gcur) {
      atomicAdd(&sums[gcur * 256 + col], acc);
      acc = 0.f; gcur = g;
    }
    acc += bf2f(hgatb[(size_t)n * 256 + col]);
  }
  atomicAdd(&sums[gcur * 256 + col], acc);
}

// ---------- mean + classifier ----------
__global__ __launch_bounds__(64) void k_classify(const float* __restrict__ sums,
    const int* __restrict__ gcnt, const float* __restrict__ W_cls,
    const float* __restrict__ b_cls, float* __restrict__ logits) {
  int g = blockIdx.x, tid = threadIdx.x;
  int hh = tid >> 5, c = tid & 31;
  float invc = 1.f / fmaxf((float)gcnt[g], 1.f);
  float acc = 0.f;
  for (int d = 0; d < D; ++d)
    acc += (sums[g * 256 + hh * D + d] * invc) * W_cls[c * D + d];
  logits[g * 64 + hh * 32 + c] = acc + b_cls[c];
}

// ---------- pairwise distance + softmax over heads (graph g vs g+64) ----------
__global__ __launch_bounds__(64) void k_final(const float* __restrict__ logits,
    float* __restrict__ out) {
  int g = threadIdx.x;
  if (g >= NG) return;
  float d[2];
  #pragma unroll
  for (int hh = 0; hh < 2; ++hh) {
    float s = 0.f;
    for (int c = 0; c < 32; ++c) {
      float df = logits[g * 64 + hh * 32 + c] - logits[(g + NG) * 64 + hh * 32 + c] + 1e-6f;
      s += df * df;
    }
    d[hh] = sqrtf(s);
  }
  float mx = fmaxf(d[0], d[1]);
  float e0 = expf(d[0] - mx), e1 = expf(d[1] - mx);
  float den = e0 + e1;
  out[g * 2] = e0 / den;
  out[g * 2 + 1] = e1 / den;
}

extern "C" void kernel_launch(void* const* d_in, const int* in_sizes, int n_in,
                              void* d_out, int out_size, void* d_ws, size_t ws_size,
                              hipStream_t stream) {
  const float* in_feat1 = (const float*)d_in[0];
  const float* in_feat2 = (const float*)d_in[1];
  const int* src1 = (const int*)d_in[2];
  const int* dst1 = (const int*)d_in[3];
  const int* ety1 = (const int*)d_in[4];
  const int* gid1 = (const int*)d_in[5];
  const int* src2 = (const int*)d_in[6];
  const int* dst2 = (const int*)d_in[7];
  const int* ety2 = (const int*)d_in[8];
  const int* gid2 = (const int*)d_in[9];
  const float* W_et = (const float*)d_in[10];
  const float* b_et = (const float*)d_in[11];
  const float* W_ih = (const float*)d_in[12];
  const float* W_hh = (const float*)d_in[13];
  const float* b_ih = (const float*)d_in[14];
  const float* b_hh = (const float*)d_in[15];
  const float* W_fc = (const float*)d_in[16];
  const float* attn_l = (const float*)d_in[17];
  const float* attn_r = (const float*)d_in[18];
  const float* gat_bias = (const float*)d_in[19];
  const float* W_cls = (const float*)d_in[20];
  const float* b_cls = (const float*)d_in[21];
  float* out = (float*)d_out;

  int N = in_sizes[0] / D;
  int E = in_sizes[2];
  int N2 = 2 * N, E2 = 2 * E;

  char* p = (char*)d_ws;
  auto alloc = [&](size_t bytes) -> void* {
    char* r = p;
    p += (bytes + 255) & ~(size_t)255;
    return (void*)r;
  };
  short* WaP  = (short*)alloc((size_t)512 * 128 * 2);
  short* WihP = (short*)alloc((size_t)384 * 128 * 2);
  short* WhhP = (short*)alloc((size_t)384 * 128 * 2);
  short* WfcP = (short*)alloc((size_t)256 * 128 * 2);
  short* hb  = (short*)alloc((size_t)N2 * D * 2);
  short* ab  = (short*)alloc((size_t)N2 * D * 2);
  short* S   = (short*)alloc((size_t)N2 * 512 * 2);     // per-etype h sums; hgatb overlays
  unsigned char* zq = (unsigned char*)alloc((size_t)N2 * 256); // fp8 zft
  float* el  = (float*)alloc((size_t)N2 * 2 * 4);
  float* er  = (float*)alloc((size_t)N2 * 2 * 4);
  float* cntf= (float*)alloc((size_t)N2 * 4 * 4);
  float* sums= (float*)alloc((size_t)NG2 * 256 * 4);
  float* logits = (float*)alloc((size_t)NG2 * 64 * 4);
  int* deg     = (int*)alloc((size_t)N2 * 4);
  int* row_ofs = (int*)alloc(((size_t)N2 + 1) * 4);
  int* cursor  = (int*)alloc((size_t)N2 * 4);
  int* gidc    = (int*)alloc((size_t)N2 * 4);
  int* gcnt    = (int*)alloc((size_t)NG2 * 4);
  int* bsum    = (int*)alloc((size_t)1024 * 4);
  int* boffs   = (int*)alloc((size_t)1024 * 4);
  int* csr_se  = (int*)alloc((size_t)E2 * 4);
  if ((size_t)(p - (char*)d_ws) > ws_size) return;

  short* hgatb = S;   // [N2,256] bf16 — overlays S (dead after last k_agemm)

  // weight packing
  k_packA512<<<dim3(32), dim3(256), 0, stream>>>(W_et, WaP);
  k_pack<<<dim3(48), dim3(256), 0, stream>>>(W_ih, WihP, 384);
  k_pack<<<dim3(48), dim3(256), 0, stream>>>(W_hh, WhhP, 384);
  k_pack<<<dim3(32), dim3(256), 0, stream>>>(W_fc, WfcP, 256);

  // CSR for merged graph
  hipMemsetAsync(deg, 0, (size_t)N2 * 4, stream);
  hipMemsetAsync(gcnt, 0, (size_t)NG2 * 4, stream);
  int eb = (E2 + 255) / 256;
  int nb = (N2 + 1023) / 1024;
  k_hist<<<dim3(eb), dim3(256), 0, stream>>>(dst1, dst2, E, N, deg);
  k_scan_a<<<dim3(nb), dim3(256), 0, stream>>>(deg, N2, bsum);
  k_scan_b<<<dim3(1), dim3(1024), 0, stream>>>(bsum, boffs, nb);
  k_scan_c<<<dim3(nb), dim3(256), 0, stream>>>(deg, boffs, row_ofs, cursor, N2);
  k_scatter<<<dim3(eb), dim3(256), 0, stream>>>(src1, dst1, ety1, src2, dst2, ety2,
                                                E, N, cursor, csr_se);
  k_fillgid<<<dim3((N2 + 255) / 256), dim3(256), 0, stream>>>(gid1, gid2, N, gidc, gcnt);

  // init h (bf16)
  k_init<<<dim3(1024), dim3(256), 0, stream>>>(in_feat1, in_feat2, hb, N * D / 4);

  int gb64 = (N2 + 63) / 64;
  int gb128 = (N2 + 127) / 128;
  int nb4 = (N2 + 3) / 4;

  for (int s = 0; s < NSTEPS; ++s) {
    k_aggS<<<dim3(nb4), dim3(256), 0, stream>>>(hb, row_ofs, csr_se, S, cntf, N2);
    k_agemm<<<dim3(gb64), dim3(256), 0, stream>>>(S, WaP, b_et, cntf, ab, N2);
    k_gru_mfma<<<dim3(gb128), dim3(256), 0, stream>>>(ab, hb, WihP, WhhP, b_ih, b_hh, N2);
  }
  k_fc_eler<<<dim3(gb128), dim3(256), 0, stream>>>(hb, WfcP, attn_l, attn_r, zq, el, er, N2);
  k_gat<<<dim3(nb4), dim3(256), 0, stream>>>(zq, el, er, row_ofs, csr_se,
                                             gat_bias, hgatb, N2);
  hipMemsetAsync(sums, 0, (size_t)NG2 * 256 * 4, stream);
  k_segred<<<dim3((N2 + 127) / 128), dim3(256), 0, stream>>>(hgatb, gidc, sums, N2);
  k_classify<<<dim3(NG2), dim3(64), 0, stream>>>(sums, gcnt, W_cls, b_cls, logits);
  k_final<<<dim3(1), dim3(64), 0, stream>>>(logits, out);
}

// Round 14
// 1331.801 us; speedup vs baseline: 1.2128x; 1.0076x over previous
//
#include <hip/hip_runtime.h>
#include <math.h>

#define D 128
#define NG 64
#define NG2 128
#define NSTEPS 5

using short8 = __attribute__((ext_vector_type(8))) short;
using f32x4  = __attribute__((ext_vector_type(4))) float;
using f32x2  = __attribute__((ext_vector_type(2))) float;

// fast, overflow-safe transcendentals (v_exp_f32 + v_rcp_f32)
__device__ __forceinline__ float sigf(float x) {
  float e = __expf(-fabsf(x));
  float inv = __fdividef(1.f, 1.f + e);
  return x >= 0.f ? inv : e * inv;
}
__device__ __forceinline__ float tanhf_fast(float x) {
  float e = __expf(-2.f * fabsf(x));
  float r = (1.f - e) * __fdividef(1.f, 1.f + e);
  return x >= 0.f ? r : -r;
}
__device__ __forceinline__ float lrelu(float x) { return x > 0.f ? x : 0.2f * x; }
__device__ __forceinline__ short f2bf(float x) {
  unsigned u = __float_as_uint(x);
  u += 0x7fff + ((u >> 16) & 1);
  return (short)(u >> 16);
}
__device__ __forceinline__ unsigned pk2(float x, float y) {
  return ((unsigned)(unsigned short)f2bf(y) << 16) | (unsigned short)f2bf(x);
}
__device__ __forceinline__ float bflo(unsigned v) { return __uint_as_float(v << 16); }
__device__ __forceinline__ float bfhi(unsigned v) { return __uint_as_float(v & 0xffff0000u); }
__device__ __forceinline__ float bf2f(short s) {
  return __uint_as_float(((unsigned)(unsigned short)s) << 16);
}
__device__ __forceinline__ unsigned char f2fp8(float x) {
  int p = __builtin_amdgcn_cvt_pk_fp8_f32(x, x, 0, false);
  return (unsigned char)(p & 0xff);
}

// ---------- init: concat(in_feat1,in_feat2) -> hb (bf16) ----------
__global__ void k_init(const float* __restrict__ f1, const float* __restrict__ f2,
                       short* __restrict__ hb, int Nd4) {
  int tot = 2 * Nd4;
  for (int i = blockIdx.x * blockDim.x + threadIdx.x; i < tot; i += gridDim.x * blockDim.x) {
    float4 v = (i < Nd4) ? ((const float4*)f1)[i] : ((const float4*)f2)[i - Nd4];
    ((uint2*)hb)[i] = make_uint2(pk2(v.x, v.y), pk2(v.z, v.w));
  }
}

// ---------- pack W[NC][128] into MFMA b-frag order, K=128 ----------
__global__ void k_pack(const float* __restrict__ W, short* __restrict__ P, int NC) {
  int n = NC * 128;
  for (int i = blockIdx.x * blockDim.x + threadIdx.x; i < n; i += gridDim.x * blockDim.x) {
    int j = i & 7;
    int lane = (i >> 3) & 63;
    int kt = (i >> 9) & 3;
    int nt = i >> 11;
    int c = nt * 16 + (lane & 15);
    int k = kt * 32 + ((lane >> 4) << 3) + j;
    P[i] = f2bf(W[c * 128 + k]);
  }
}

// ---------- pack stacked W_et [4][128 out][128 in] as B[K=512][out=128] frags ----------
__global__ void k_packA512(const float* __restrict__ W_et, short* __restrict__ P) {
  int n = 128 * 512;
  for (int i = blockIdx.x * blockDim.x + threadIdx.x; i < n; i += gridDim.x * blockDim.x) {
    int j = i & 7;
    int lane = (i >> 3) & 63;
    int kt = (i >> 9) & 15;
    int nt = i >> 13;
    int c = nt * 16 + (lane & 15);
    int k = kt * 32 + ((lane >> 4) << 3) + j;
    P[i] = f2bf(W_et[(k >> 7) * 16384 + c * 128 + (k & 127)]);
  }
}

// ---------- CSR build over merged graph ----------
__global__ void k_hist(const int* __restrict__ dst1, const int* __restrict__ dst2,
                       int E, int N, int* __restrict__ deg) {
  for (int e = blockIdx.x * blockDim.x + threadIdx.x; e < 2 * E; e += gridDim.x * blockDim.x) {
    int d = (e < E) ? dst1[e] : dst2[e - E] + N;
    atomicAdd(&deg[d], 1);
  }
}

__global__ __launch_bounds__(256) void k_scan_a(const int* __restrict__ deg, int n,
                                                int* __restrict__ bsum) {
  int base = blockIdx.x * 1024 + threadIdx.x * 4;
  int s = 0;
  if (base + 3 < n) {
    int4 v = *(const int4*)(deg + base);
    s = v.x + v.y + v.z + v.w;
  } else {
    for (int k = 0; k < 4; ++k) if (base + k < n) s += deg[base + k];
  }
  #pragma unroll
  for (int off = 32; off; off >>= 1) s += __shfl_xor(s, off);
  __shared__ int ws[4];
  if ((threadIdx.x & 63) == 0) ws[threadIdx.x >> 6] = s;
  __syncthreads();
  if (threadIdx.x == 0) bsum[blockIdx.x] = ws[0] + ws[1] + ws[2] + ws[3];
}

__global__ __launch_bounds__(1024) void k_scan_b(const int* __restrict__ bsum,
                                                 int* __restrict__ boffs, int nb) {
  int tid = threadIdx.x;
  int v = (tid < nb) ? bsum[tid] : 0;
  int lane = tid & 63, wv = tid >> 6;
  int x = v;
  #pragma unroll
  for (int off = 1; off < 64; off <<= 1) {
    int y = __shfl_up(x, off);
    if (lane >= off) x += y;
  }
  __shared__ int wsum[16];
  if (lane == 63) wsum[wv] = x;
  __syncthreads();
  if (tid < 16) {
    int u = wsum[tid];
    #pragma unroll
    for (int off = 1; off < 16; off <<= 1) {
      int y = __shfl_up(u, off);
      if (tid >= off) u += y;
    }
    wsum[tid] = u;
  }
  __syncthreads();
  int woff = wv ? wsum[wv - 1] : 0;
  if (tid < nb) boffs[tid] = woff + x - v;
}

__global__ __launch_bounds__(256) void k_scan_c(const int* __restrict__ deg,
    const int* __restrict__ boffs, int* __restrict__ row_ofs,
    int* __restrict__ cursor, int n) {
  int base = blockIdx.x * 1024 + threadIdx.x * 4;
  int v[4] = {0, 0, 0, 0};
  if (base + 3 < n) {
    int4 t = *(const int4*)(deg + base);
    v[0] = t.x; v[1] = t.y; v[2] = t.z; v[3] = t.w;
  } else {
    for (int k = 0; k < 4; ++k) if (base + k < n) v[k] = deg[base + k];
  }
  int s = v[0] + v[1] + v[2] + v[3];
  int lane = threadIdx.x & 63, wv = threadIdx.x >> 6;
  int x = s;
  #pragma unroll
  for (int off = 1; off < 64; off <<= 1) {
    int y = __shfl_up(x, off);
    if (lane >= off) x += y;
  }
  __shared__ int wsum[4];
  if (lane == 63) wsum[wv] = x;
  __syncthreads();
  int woff = 0;
  for (int w = 0; w < wv; ++w) woff += wsum[w];
  int run = boffs[blockIdx.x] + woff + x - s;
  #pragma unroll
  for (int k = 0; k < 4; ++k) {
    int i = base + k;
    if (i < n) {
      cursor[i] = run;
      run += v[k];
      row_ofs[i + 1] = run;
    }
  }
  if (blockIdx.x == 0 && threadIdx.x == 0) row_ofs[0] = 0;
}

// scatter: single merged array csr_se = src*4 + etype
__global__ void k_scatter(const int* __restrict__ src1, const int* __restrict__ dst1,
                          const int* __restrict__ ety1, const int* __restrict__ src2,
                          const int* __restrict__ dst2, const int* __restrict__ ety2,
                          int E, int N, int* __restrict__ cursor,
                          int* __restrict__ csr_se) {
  for (int e = blockIdx.x * blockDim.x + threadIdx.x; e < 2 * E; e += gridDim.x * blockDim.x) {
    int s, d, et;
    if (e < E) { s = src1[e]; d = dst1[e]; et = ety1[e]; }
    else { s = src2[e - E] + N; d = dst2[e - E] + N; et = ety2[e - E]; }
    int p = atomicAdd(&cursor[d], 1);
    csr_se[p] = s * 4 + et;
  }
}

// ---------- merged gid array [2N] + per-graph counts [128] ----------
__global__ void k_fillgid(const int* __restrict__ gid1, const int* __restrict__ gid2,
                          int N, int* __restrict__ gidc, int* __restrict__ gcnt) {
  __shared__ int cnt[NG2];
  int t = threadIdx.x;
  if (t < NG2) cnt[t] = 0;
  __syncthreads();
  int i = blockIdx.x * 256 + t;
  if (i < 2 * N) {
    int g = (i < N) ? gid1[i] : gid2[i - N] + NG;
    gidc[i] = g;
    atomicAdd(&cnt[g], 1);
  }
  __syncthreads();
  if (t < NG2 && cnt[t]) atomicAdd(&gcnt[t], cnt[t]);
}

// ---------- per-etype neighbor sums + counts; readlane, 8x + 4x + 1x MLP tiers ----------
__global__ __launch_bounds__(256) void k_aggS(const short* __restrict__ hb,
    const int* __restrict__ row_ofs, const int* __restrict__ csr_se,
    short* __restrict__ S, float* __restrict__ cntf, int N) {
  int node = blockIdx.x * 4 + (threadIdx.x >> 6);
  int lane = threadIdx.x & 63;
  if (node >= N) return;
  int beg = row_ofs[node], end = row_ofs[node + 1];
  float a0x = 0.f, a0y = 0.f, a1x = 0.f, a1y = 0.f;
  float a2x = 0.f, a2y = 0.f, a3x = 0.f, a3y = 0.f;
  int c0 = 0, c1 = 0, c2 = 0, c3 = 0;
  #define ACC(ET, VX, VY) do { \
      if (ET == 0)      { a0x += VX; a0y += VY; ++c0; } \
      else if (ET == 1) { a1x += VX; a1y += VY; ++c1; } \
      else if (ET == 2) { a2x += VX; a2y += VY; ++c2; } \
      else              { a3x += VX; a3y += VY; ++c3; } } while (0)
  for (int base = beg; base < end; base += 64) {
    int nv = end - base; if (nv > 64) nv = 64;
    int r = (lane < nv) ? csr_se[base + lane] : 0;
    int j = 0;
    for (; j + 8 <= nv; j += 8) {
      int rr0 = __builtin_amdgcn_readlane(r, j + 0);
      int rr1 = __builtin_amdgcn_readlane(r, j + 1);
      int rr2 = __builtin_amdgcn_readlane(r, j + 2);
      int rr3 = __builtin_amdgcn_readlane(r, j + 3);
      int rr4 = __builtin_amdgcn_readlane(r, j + 4);
      int rr5 = __builtin_amdgcn_readlane(r, j + 5);
      int rr6 = __builtin_amdgcn_readlane(r, j + 6);
      int rr7 = __builtin_amdgcn_readlane(r, j + 7);
      unsigned v0 = ((const unsigned*)(hb + (size_t)(rr0 >> 2) * 128))[lane];
      unsigned v1 = ((const unsigned*)(hb + (size_t)(rr1 >> 2) * 128))[lane];
      unsigned v2 = ((const unsigned*)(hb + (size_t)(rr2 >> 2) * 128))[lane];
      unsigned v3 = ((const unsigned*)(hb + (size_t)(rr3 >> 2) * 128))[lane];
      unsigned v4 = ((const unsigned*)(hb + (size_t)(rr4 >> 2) * 128))[lane];
      unsigned v5 = ((const unsigned*)(hb + (size_t)(rr5 >> 2) * 128))[lane];
      unsigned v6 = ((const unsigned*)(hb + (size_t)(rr6 >> 2) * 128))[lane];
      unsigned v7 = ((const unsigned*)(hb + (size_t)(rr7 >> 2) * 128))[lane];
      ACC(rr0 & 3, bflo(v0), bfhi(v0));
      ACC(rr1 & 3, bflo(v1), bfhi(v1));
      ACC(rr2 & 3, bflo(v2), bfhi(v2));
      ACC(rr3 & 3, bflo(v3), bfhi(v3));
      ACC(rr4 & 3, bflo(v4), bfhi(v4));
      ACC(rr5 & 3, bflo(v5), bfhi(v5));
      ACC(rr6 & 3, bflo(v6), bfhi(v6));
      ACC(rr7 & 3, bflo(v7), bfhi(v7));
    }
    for (; j + 4 <= nv; j += 4) {
      int rr0 = __builtin_amdgcn_readlane(r, j + 0);
      int rr1 = __builtin_amdgcn_readlane(r, j + 1);
      int rr2 = __builtin_amdgcn_readlane(r, j + 2);
      int rr3 = __builtin_amdgcn_readlane(r, j + 3);
      unsigned v0 = ((const unsigned*)(hb + (size_t)(rr0 >> 2) * 128))[lane];
      unsigned v1 = ((const unsigned*)(hb + (size_t)(rr1 >> 2) * 128))[lane];
      unsigned v2 = ((const unsigned*)(hb + (size_t)(rr2 >> 2) * 128))[lane];
      unsigned v3 = ((const unsigned*)(hb + (size_t)(rr3 >> 2) * 128))[lane];
      ACC(rr0 & 3, bflo(v0), bfhi(v0));
      ACC(rr1 & 3, bflo(v1), bfhi(v1));
      ACC(rr2 & 3, bflo(v2), bfhi(v2));
      ACC(rr3 & 3, bflo(v3), bfhi(v3));
    }
    for (; j < nv; ++j) {
      int rr = __builtin_amdgcn_readlane(r, j);
      unsigned v = ((const unsigned*)(hb + (size_t)(rr >> 2) * 128))[lane];
      ACC(rr & 3, bflo(v), bfhi(v));
    }
  }
  #undef ACC
  size_t b = (size_t)node * 512;
  ((unsigned*)(S + b      ))[lane] = pk2(a0x, a0y);
  ((unsigned*)(S + b + 128))[lane] = pk2(a1x, a1y);
  ((unsigned*)(S + b + 256))[lane] = pk2(a2x, a2y);
  ((unsigned*)(S + b + 384))[lane] = pk2(a3x, a3y);
  if (lane == 0) {
    float4 cv = {(float)c0, (float)c1, (float)c2, (float)c3};
    *(float4*)(cntf + (size_t)node * 4) = cv;
  }
}

// ---------- a = S[M,512] @ Wa (K=512 MFMA) + cnt_et·b_et  -> ab (bf16) ----------
__global__ __launch_bounds__(256) void k_agemm(const short* __restrict__ S,
    const short* __restrict__ WaP, const float* __restrict__ b_et,
    const float* __restrict__ cntf, short* __restrict__ ab, int M) {
  int tid = threadIdx.x;
  int lane = tid & 63, wave = tid >> 6;
  int row0 = blockIdx.x * 64 + wave * 16;
  int quad = lane >> 4, l15 = lane & 15;
  int ar = row0 + l15; if (ar >= M) ar = M - 1;
  short8 sf[16];
  #pragma unroll
  for (int kt = 0; kt < 16; ++kt)
    sf[kt] = *(const short8*)(S + (size_t)ar * 512 + kt * 32 + quad * 8);
  float4 cn[4];
  #pragma unroll
  for (int reg = 0; reg < 4; ++reg) {
    int r = row0 + quad * 4 + reg; if (r >= M) r = M - 1;
    cn[reg] = *(const float4*)(cntf + (size_t)r * 4);
  }
  for (int nt = 0; nt < 8; ++nt) {
    f32x4 acc = {0.f, 0.f, 0.f, 0.f};
    #pragma unroll
    for (int kt = 0; kt < 16; ++kt) {
      short8 b = *(const short8*)(WaP + (((size_t)(nt * 16 + kt) * 64) + lane) * 8);
      acc = __builtin_amdgcn_mfma_f32_16x16x32_bf16(sf[kt], b, acc, 0, 0, 0);
    }
    int c = nt * 16 + l15;
    float be0 = b_et[c], be1 = b_et[128 + c], be2 = b_et[256 + c], be3 = b_et[384 + c];
    #pragma unroll
    for (int reg = 0; reg < 4; ++reg) {
      int r = row0 + quad * 4 + reg;
      if (r < M) {
        float v = acc[reg] + cn[reg].x * be0 + cn[reg].y * be1
                           + cn[reg].z * be2 + cn[reg].w * be3;
        ab[(size_t)r * 128 + c] = f2bf(v);
      }
    }
  }
}

// ---------- fused GRU via MFMA, 32 rows/wave, bf16 recurrent state ----------
__global__ __launch_bounds__(256) void k_gru_mfma(const short* __restrict__ ab,
    short* __restrict__ hb,
    const short* __restrict__ Pih, const short* __restrict__ Phh,
    const float* __restrict__ b_ih, const float* __restrict__ b_hh, int M) {
  int tid = threadIdx.x;
  int lane = tid & 63, wave = tid >> 6;
  int row0 = blockIdx.x * 128 + wave * 32;
  int quad = lane >> 4, l15 = lane & 15;
  short8 fa[2][4], fh[2][4];
  #pragma unroll
  for (int rt = 0; rt < 2; ++rt) {
    int ar = row0 + rt * 16 + l15; if (ar >= M) ar = M - 1;
    #pragma unroll
    for (int kt = 0; kt < 4; ++kt) {
      fa[rt][kt] = *(const short8*)(ab + (size_t)ar * 128 + kt * 32 + quad * 8);
      fh[rt][kt] = *(const short8*)(hb + (size_t)ar * 128 + kt * 32 + quad * 8);
    }
  }
  for (int nt = 0; nt < 8; ++nt) {
    f32x4 accr[2], accz[2], acci[2], acch[2];
    #pragma unroll
    for (int rt = 0; rt < 2; ++rt) {
      accr[rt] = {0.f,0.f,0.f,0.f}; accz[rt] = {0.f,0.f,0.f,0.f};
      acci[rt] = {0.f,0.f,0.f,0.f}; acch[rt] = {0.f,0.f,0.f,0.f};
    }
    #pragma unroll
    for (int kt = 0; kt < 4; ++kt) {
      size_t li = ((size_t)lane) * 8;
      short8 wr = *(const short8*)(Pih + ((size_t)((nt     ) * 4 + kt) * 64) * 8 + li);
      short8 wz = *(const short8*)(Pih + ((size_t)((nt +  8) * 4 + kt) * 64) * 8 + li);
      short8 wn = *(const short8*)(Pih + ((size_t)((nt + 16) * 4 + kt) * 64) * 8 + li);
      short8 ur = *(const short8*)(Phh + ((size_t)((nt     ) * 4 + kt) * 64) * 8 + li);
      short8 uz = *(const short8*)(Phh + ((size_t)((nt +  8) * 4 + kt) * 64) * 8 + li);
      short8 un = *(const short8*)(Phh + ((size_t)((nt + 16) * 4 + kt) * 64) * 8 + li);
      #pragma unroll
      for (int rt = 0; rt < 2; ++rt) {
        accr[rt] = __builtin_amdgcn_mfma_f32_16x16x32_bf16(fa[rt][kt], wr, accr[rt], 0, 0, 0);
        accr[rt] = __builtin_amdgcn_mfma_f32_16x16x32_bf16(fh[rt][kt], ur, accr[rt], 0, 0, 0);
        accz[rt] = __builtin_amdgcn_mfma_f32_16x16x32_bf16(fa[rt][kt], wz, accz[rt], 0, 0, 0);
        accz[rt] = __builtin_amdgcn_mfma_f32_16x16x32_bf16(fh[rt][kt], uz, accz[rt], 0, 0, 0);
        acci[rt] = __builtin_amdgcn_mfma_f32_16x16x32_bf16(fa[rt][kt], wn, acci[rt], 0, 0, 0);
        acch[rt] = __builtin_amdgcn_mfma_f32_16x16x32_bf16(fh[rt][kt], un, acch[rt], 0, 0, 0);
      }
    }
    int c = nt * 16 + l15;
    float bir = b_ih[c],      bhr = b_hh[c];
    float biz = b_ih[c+128],  bhz = b_hh[c+128];
    float bin_= b_ih[c+256],  bhn = b_hh[c+256];
    #pragma unroll
    for (int rt = 0; rt < 2; ++rt) {
      #pragma unroll
      for (int reg = 0; reg < 4; ++reg) {
        int r = row0 + rt * 16 + quad * 4 + reg;
        if (r < M) {
          float rg = sigf(accr[rt][reg] + bir + bhr);
          float zg = sigf(accz[rt][reg] + biz + bhz);
          float ng = tanhf_fast(acci[rt][reg] + bin_ + rg * (acch[rt][reg] + bhn));
          float hold = bf2f(hb[(size_t)r * 128 + c]);
          float hn2 = (1.f - zg) * ng + zg * hold;
          hb[(size_t)r * 128 + c] = f2bf(hn2);
        }
      }
    }
  }
}

// ---------- fc GEMM (256 cols) fused normalize+sigmoid + el/er; zq out is fp8 ----------
__global__ __launch_bounds__(256) void k_fc_eler(const short* __restrict__ Ab,
    const short* __restrict__ Bp, const float* __restrict__ attn_l,
    const float* __restrict__ attn_r, unsigned char* __restrict__ zq,
    float* __restrict__ el, float* __restrict__ er, int M) {
  int tid = threadIdx.x;
  int lane = tid & 63, wave = tid >> 6;
  int row0 = blockIdx.x * 128 + wave * 32;
  int quad = lane >> 4, l15 = lane & 15;
  short8 af[2][4];
  #pragma unroll
  for (int rt = 0; rt < 2; ++rt) {
    int ar = row0 + rt * 16 + l15; if (ar >= M) ar = M - 1;
    #pragma unroll
    for (int kt = 0; kt < 4; ++kt)
      af[rt][kt] = *(const short8*)(Ab + (size_t)ar * 128 + kt * 32 + quad * 8);
  }
  #pragma unroll
  for (int rt = 0; rt < 2; ++rt) {
    float ss = 0.f;
    #pragma unroll
    for (int kt = 0; kt < 4; ++kt)
      #pragma unroll
      for (int j = 0; j < 8; ++j) {
        float x = bf2f(af[rt][kt][j]);
        ss += x * x;
      }
    ss += __shfl_xor(ss, 16);
    ss += __shfl_xor(ss, 32);
    float inv = 1.f / fmaxf(sqrtf(ss), 1e-12f);
    #pragma unroll
    for (int kt = 0; kt < 4; ++kt)
      #pragma unroll
      for (int j = 0; j < 8; ++j)
        af[rt][kt][j] = f2bf(sigf(bf2f(af[rt][kt][j]) * inv));
  }
  float elp[2][2][4] = {};
  float erp[2][2][4] = {};
  for (int nt = 0; nt < 16; ++nt) {
    f32x4 a0 = {0.f,0.f,0.f,0.f}, a1 = {0.f,0.f,0.f,0.f};
    #pragma unroll
    for (int kt = 0; kt < 4; ++kt) {
      short8 b = *(const short8*)(Bp + (((size_t)(nt * 4 + kt) * 64) + lane) * 8);
      a0 = __builtin_amdgcn_mfma_f32_16x16x32_bf16(af[0][kt], b, a0, 0, 0, 0);
      a1 = __builtin_amdgcn_mfma_f32_16x16x32_bf16(af[1][kt], b, a1, 0, 0, 0);
    }
    int head = nt >> 3;
    int colh = (nt & 7) * 16 + l15;
    float alv = attn_l[head * 128 + colh];
    float arv = attn_r[head * 128 + colh];
    int c = nt * 16 + l15;
    #pragma unroll
    for (int rt = 0; rt < 2; ++rt) {
      f32x4 acc = rt ? a1 : a0;
      #pragma unroll
      for (int reg = 0; reg < 4; ++reg) {
        int r = row0 + rt * 16 + quad * 4 + reg;
        if (r < M) zq[(size_t)r * 256 + c] = f2fp8(acc[reg]);
        elp[rt][head][reg] += acc[reg] * alv;
        erp[rt][head][reg] += acc[reg] * arv;
      }
    }
  }
  #pragma unroll
  for (int off = 1; off < 16; off <<= 1) {
    #pragma unroll
    for (int rt = 0; rt < 2; ++rt)
      #pragma unroll
      for (int h = 0; h < 2; ++h)
        #pragma unroll
        for (int reg = 0; reg < 4; ++reg) {
          elp[rt][h][reg] += __shfl_xor(elp[rt][h][reg], off);
          erp[rt][h][reg] += __shfl_xor(erp[rt][h][reg], off);
        }
  }
  if (l15 == 0) {
    #pragma unroll
    for (int rt = 0; rt < 2; ++rt)
      #pragma unroll
      for (int h = 0; h < 2; ++h)
        #pragma unroll
        for (int reg = 0; reg < 4; ++reg) {
          int r = row0 + rt * 16 + quad * 4 + reg;
          if (r < M) {
            el[r * 2 + h] = elp[rt][h][reg];
            er[r * 2 + h] = erp[rt][h][reg];
          }
        }
  }
}

// ---------- GAT aggregation — R8-exact inner loop (shfl broadcast, VGPR 24) ----------
__global__ __launch_bounds__(256) void k_gat(const unsigned char* __restrict__ zq,
    const float* __restrict__ el, const float* __restrict__ er,
    const int* __restrict__ row_ofs, const int* __restrict__ csr_se,
    const float* __restrict__ gat_bias, short* __restrict__ outb, int N) {
  int node = blockIdx.x * 4 + (threadIdx.x >> 6);
  int lane = threadIdx.x & 63;
  if (node >= N) return;
  int beg = row_ofs[node], end = row_ofs[node + 1];
  float2 ern = ((const float2*)er)[node];
  float m0 = -INFINITY, m1 = -INFINITY, l0 = 0.f, l1 = 0.f;
  float4 acc = {0.f, 0.f, 0.f, 0.f};
  int head = lane >> 5;
  for (int base = beg; base < end; base += 64) {
    int nv = end - base; if (nv > 64) nv = 64;
    int sidx = (lane < nv) ? (csr_se[base + lane] >> 2) : 0;
    float e0 = -INFINITY, e1 = -INFINITY;
    if (lane < nv) {
      float2 els = ((const float2*)el)[sidx];
      e0 = lrelu(els.x + ern.x);
      e1 = lrelu(els.y + ern.y);
    }
    float c0 = e0, c1 = e1;
    #pragma unroll
    for (int off = 32; off; off >>= 1) {
      c0 = fmaxf(c0, __shfl_xor(c0, off));
      c1 = fmaxf(c1, __shfl_xor(c1, off));
    }
    float nm0 = fmaxf(m0, c0), nm1 = fmaxf(m1, c1);
    float s0 = expf(m0 - nm0), s1 = expf(m1 - nm1);
    float p0 = (lane < nv) ? expf(e0 - nm0) : 0.f;
    float p1 = (lane < nv) ? expf(e1 - nm1) : 0.f;
    float t0 = p0, t1 = p1;
    #pragma unroll
    for (int off = 32; off; off >>= 1) { t0 += __shfl_xor(t0, off); t1 += __shfl_xor(t1, off); }
    float sc = head ? s1 : s0;
    acc.x *= sc; acc.y *= sc; acc.z *= sc; acc.w *= sc;
    l0 = l0 * s0 + t0; l1 = l1 * s1 + t1;
    m0 = nm0; m1 = nm1;
    #pragma unroll 4
    for (int j = 0; j < nv; ++j) {
      int sj = __shfl(sidx, j);
      float pj0 = __shfl(p0, j), pj1 = __shfl(p1, j);
      float w = head ? pj1 : pj0;
      unsigned zv = ((const unsigned*)(zq + (size_t)sj * 256))[lane];
      f32x2 lo = __builtin_amdgcn_cvt_pk_f32_fp8(zv, false);
      f32x2 hi = __builtin_amdgcn_cvt_pk_f32_fp8(zv, true);
      acc.x += w * lo[0]; acc.y += w * lo[1];
      acc.z += w * hi[0]; acc.w += w * hi[1];
    }
  }
  float inv0 = (l0 > 0.f) ? 1.f / l0 : 0.f;
  float inv1 = (l1 > 0.f) ? 1.f / l1 : 0.f;
  float inv = head ? inv1 : inv0;
  float4 b = ((const float4*)gat_bias)[lane];
  float ox = fmaxf(acc.x * inv + b.x, 0.f);
  float oy = fmaxf(acc.y * inv + b.y, 0.f);
  float oz = fmaxf(acc.z * inv + b.z, 0.f);
  float ow = fmaxf(acc.w * inv + b.w, 0.f);
  ((uint2*)(outb + (size_t)node * 256))[lane] = make_uint2(pk2(ox, oy), pk2(oz, ow));
}

// ---------- parallel segmented per-graph sums (bf16 input) ----------
__global__ __launch_bounds__(256) void k_segred(const short* __restrict__ hgatb,
    const int* __restrict__ gidc, float* __restrict__ sums, int NT2) {
  int node0 = blockIdx.x * 128;
  int col = threadIdx.x;
  int end = node0 + 128; if (end > NT2) end = NT2;
  if (node0 >= NT2) return;
  float acc = 0.f;
  int gcur = gidc[node0];
  for (int n = node0; n < end; ++n) {
    int g = gidc[n];
    if (g != gcur) {
      atomicAdd(&sums[gcur * 256 + col], acc);
      acc = 0.f; gcur = g;
    }
    acc += bf2f(hgatb[(size_t)n * 256 + col]);
  }
  atomicAdd(&sums[gcur * 256 + col], acc);
}

// ---------- mean + classifier ----------
__global__ __launch_bounds__(64) void k_classify(const float* __restrict__ sums,
    const int* __restrict__ gcnt, const float* __restrict__ W_cls,
    const float* __restrict__ b_cls, float* __restrict__ logits) {
  int g = blockIdx.x, tid = threadIdx.x;
  int hh = tid >> 5, c = tid & 31;
  float invc = 1.f / fmaxf((float)gcnt[g], 1.f);
  float acc = 0.f;
  for (int d = 0; d < D; ++d)
    acc += (sums[g * 256 + hh * D + d] * invc) * W_cls[c * D + d];
  logits[g * 64 + hh * 32 + c] = acc + b_cls[c];
}

// ---------- pairwise distance + softmax over heads (graph g vs g+64) ----------
__global__ __launch_bounds__(64) void k_final(const float* __restrict__ logits,
    float* __restrict__ out) {
  int g = threadIdx.x;
  if (g >= NG) return;
  float d[2];
  #pragma unroll
  for (int hh = 0; hh < 2; ++hh) {
    float s = 0.f;
    for (int c = 0; c < 32; ++c) {
      float df = logits[g * 64 + hh * 32 + c] - logits[(g + NG) * 64 + hh * 32 + c] + 1e-6f;
      s += df * df;
    }
    d[hh] = sqrtf(s);
  }
  float mx = fmaxf(d[0], d[1]);
  float e0 = expf(d[0] - mx), e1 = expf(d[1] - mx);
  float den = e0 + e1;
  out[g * 2] = e0 / den;
  out[g * 2 + 1] = e1 / den;
}

extern "C" void kernel_launch(void* const* d_in, const int* in_sizes, int n_in,
                              void* d_out, int out_size, void* d_ws, size_t ws_size,
                              hipStream_t stream) {
  const float* in_feat1 = (const float*)d_in[0];
  const float* in_feat2 = (const float*)d_in[1];
  const int* src1 = (const int*)d_in[2];
  const int* dst1 = (const int*)d_in[3];
  const int* ety1 = (const int*)d_in[4];
  const int* gid1 = (const int*)d_in[5];
  const int* src2 = (const int*)d_in[6];
  const int* dst2 = (const int*)d_in[7];
  const int* ety2 = (const int*)d_in[8];
  const int* gid2 = (const int*)d_in[9];
  const float* W_et = (const float*)d_in[10];
  const float* b_et = (const float*)d_in[11];
  const float* W_ih = (const float*)d_in[12];
  const float* W_hh = (const float*)d_in[13];
  const float* b_ih = (const float*)d_in[14];
  const float* b_hh = (const float*)d_in[15];
  const float* W_fc = (const float*)d_in[16];
  const float* attn_l = (const float*)d_in[17];
  const float* attn_r = (const float*)d_in[18];
  const float* gat_bias = (const float*)d_in[19];
  const float* W_cls = (const float*)d_in[20];
  const float* b_cls = (const float*)d_in[21];
  float* out = (float*)d_out;

  int N = in_sizes[0] / D;
  int E = in_sizes[2];
  int N2 = 2 * N, E2 = 2 * E;

  char* p = (char*)d_ws;
  auto alloc = [&](size_t bytes) -> void* {
    char* r = p;
    p += (bytes + 255) & ~(size_t)255;
    return (void*)r;
  };
  short* WaP  = (short*)alloc((size_t)512 * 128 * 2);
  short* WihP = (short*)alloc((size_t)384 * 128 * 2);
  short* WhhP = (short*)alloc((size_t)384 * 128 * 2);
  short* WfcP = (short*)alloc((size_t)256 * 128 * 2);
  short* hb  = (short*)alloc((size_t)N2 * D * 2);
  short* ab  = (short*)alloc((size_t)N2 * D * 2);
  short* S   = (short*)alloc((size_t)N2 * 512 * 2);     // per-etype h sums; hgatb overlays
  unsigned char* zq = (unsigned char*)alloc((size_t)N2 * 256); // fp8 zft
  float* el  = (float*)alloc((size_t)N2 * 2 * 4);
  float* er  = (float*)alloc((size_t)N2 * 2 * 4);
  float* cntf= (float*)alloc((size_t)N2 * 4 * 4);
  float* sums= (float*)alloc((size_t)NG2 * 256 * 4);
  float* logits = (float*)alloc((size_t)NG2 * 64 * 4);
  int* deg     = (int*)alloc((size_t)N2 * 4);
  int* row_ofs = (int*)alloc(((size_t)N2 + 1) * 4);
  int* cursor  = (int*)alloc((size_t)N2 * 4);
  int* gidc    = (int*)alloc((size_t)N2 * 4);
  int* gcnt    = (int*)alloc((size_t)NG2 * 4);
  int* bsum    = (int*)alloc((size_t)1024 * 4);
  int* boffs   = (int*)alloc((size_t)1024 * 4);
  int* csr_se  = (int*)alloc((size_t)E2 * 4);
  if ((size_t)(p - (char*)d_ws) > ws_size) return;

  short* hgatb = S;   // [N2,256] bf16 — overlays S (dead after last k_agemm)

  // weight packing
  k_packA512<<<dim3(32), dim3(256), 0, stream>>>(W_et, WaP);
  k_pack<<<dim3(48), dim3(256), 0, stream>>>(W_ih, WihP, 384);
  k_pack<<<dim3(48), dim3(256), 0, stream>>>(W_hh, WhhP, 384);
  k_pack<<<dim3(32), dim3(256), 0, stream>>>(W_fc, WfcP, 256);

  // CSR for merged graph
  hipMemsetAsync(deg, 0, (size_t)N2 * 4, stream);
  hipMemsetAsync(gcnt, 0, (size_t)NG2 * 4, stream);
  int eb = (E2 + 255) / 256;
  int nb = (N2 + 1023) / 1024;
  k_hist<<<dim3(eb), dim3(256), 0, stream>>>(dst1, dst2, E, N, deg);
  k_scan_a<<<dim3(nb), dim3(256), 0, stream>>>(deg, N2, bsum);
  k_scan_b<<<dim3(1), dim3(1024), 0, stream>>>(bsum, boffs, nb);
  k_scan_c<<<dim3(nb), dim3(256), 0, stream>>>(deg, boffs, row_ofs, cursor, N2);
  k_scatter<<<dim3(eb), dim3(256), 0, stream>>>(src1, dst1, ety1, src2, dst2, ety2,
                                                E, N, cursor, csr_se);
  k_fillgid<<<dim3((N2 + 255) / 256), dim3(256), 0, stream>>>(gid1, gid2, N, gidc, gcnt);

  // init h (bf16)
  k_init<<<dim3(1024), dim3(256), 0, stream>>>(in_feat1, in_feat2, hb, N * D / 4);

  int gb64 = (N2 + 63) / 64;
  int gb128 = (N2 + 127) / 128;
  int nb4 = (N2 + 3) / 4;

  for (int s = 0; s < NSTEPS; ++s) {
    k_aggS<<<dim3(nb4), dim3(256), 0, stream>>>(hb, row_ofs, csr_se, S, cntf, N2);
    k_agemm<<<dim3(gb64), dim3(256), 0, stream>>>(S, WaP, b_et, cntf, ab, N2);
    k_gru_mfma<<<dim3(gb128), dim3(256), 0, stream>>>(ab, hb, WihP, WhhP, b_ih, b_hh, N2);
  }
  k_fc_eler<<<dim3(gb128), dim3(256), 0, stream>>>(hb, WfcP, attn_l, attn_r, zq, el, er, N2);
  k_gat<<<dim3(nb4), dim3(256), 0, stream>>>(zq, el, er, row_ofs, csr_se,
                                             gat_bias, hgatb, N2);
  hipMemsetAsync(sums, 0, (size_t)NG2 * 256 * 4, stream);
  k_segred<<<dim3((N2 + 127) / 128), dim3(256), 0, stream>>>(hgatb, gidc, sums, N2);
  k_classify<<<dim3(NG2), dim3(64), 0, stream>>>(sums, gcnt, W_cls, b_cls, logits);
  k_final<<<dim3(1), dim3(64), 0, stream>>>(logits, out);
}

// Round 15
// 1329.176 us; speedup vs baseline: 1.2152x; 1.0020x over previous
//
#include <hip/hip_runtime.h>
#include <math.h>

#define D 128
#define NG 64
#define NG2 128
#define NSTEPS 5

using short8 = __attribute__((ext_vector_type(8))) short;
using f32x4  = __attribute__((ext_vector_type(4))) float;
using f32x2  = __attribute__((ext_vector_type(2))) float;

// fast, overflow-safe transcendentals (v_exp_f32 + v_rcp_f32)
__device__ __forceinline__ float sigf(float x) {
  float e = __expf(-fabsf(x));
  float inv = __fdividef(1.f, 1.f + e);
  return x >= 0.f ? inv : e * inv;
}
__device__ __forceinline__ float tanhf_fast(float x) {
  float e = __expf(-2.f * fabsf(x));
  float r = (1.f - e) * __fdividef(1.f, 1.f + e);
  return x >= 0.f ? r : -r;
}
__device__ __forceinline__ float lrelu(float x) { return x > 0.f ? x : 0.2f * x; }
__device__ __forceinline__ short f2bf(float x) {
  unsigned u = __float_as_uint(x);
  u += 0x7fff + ((u >> 16) & 1);
  return (short)(u >> 16);
}
__device__ __forceinline__ unsigned pk2(float x, float y) {
  return ((unsigned)(unsigned short)f2bf(y) << 16) | (unsigned short)f2bf(x);
}
__device__ __forceinline__ float bflo(unsigned v) { return __uint_as_float(v << 16); }
__device__ __forceinline__ float bfhi(unsigned v) { return __uint_as_float(v & 0xffff0000u); }
__device__ __forceinline__ float bf2f(short s) {
  return __uint_as_float(((unsigned)(unsigned short)s) << 16);
}
__device__ __forceinline__ unsigned char f2fp8(float x) {
  int p = __builtin_amdgcn_cvt_pk_fp8_f32(x, x, 0, false);
  return (unsigned char)(p & 0xff);
}

// ---------- init: concat(in_feat1,in_feat2) -> hb (bf16) ----------
__global__ void k_init(const float* __restrict__ f1, const float* __restrict__ f2,
                       short* __restrict__ hb, int Nd4) {
  int tot = 2 * Nd4;
  for (int i = blockIdx.x * blockDim.x + threadIdx.x; i < tot; i += gridDim.x * blockDim.x) {
    float4 v = (i < Nd4) ? ((const float4*)f1)[i] : ((const float4*)f2)[i - Nd4];
    ((uint2*)hb)[i] = make_uint2(pk2(v.x, v.y), pk2(v.z, v.w));
  }
}

// ---------- pack W[NC][128] into MFMA b-frag order, K=128 ----------
__global__ void k_pack(const float* __restrict__ W, short* __restrict__ P, int NC) {
  int n = NC * 128;
  for (int i = blockIdx.x * blockDim.x + threadIdx.x; i < n; i += gridDim.x * blockDim.x) {
    int j = i & 7;
    int lane = (i >> 3) & 63;
    int kt = (i >> 9) & 3;
    int nt = i >> 11;
    int c = nt * 16 + (lane & 15);
    int k = kt * 32 + ((lane >> 4) << 3) + j;
    P[i] = f2bf(W[c * 128 + k]);
  }
}

// ---------- pack stacked W_et [4][128 out][128 in] as B[K=512][out=128] frags ----------
__global__ void k_packA512(const float* __restrict__ W_et, short* __restrict__ P) {
  int n = 128 * 512;
  for (int i = blockIdx.x * blockDim.x + threadIdx.x; i < n; i += gridDim.x * blockDim.x) {
    int j = i & 7;
    int lane = (i >> 3) & 63;
    int kt = (i >> 9) & 15;
    int nt = i >> 13;
    int c = nt * 16 + (lane & 15);
    int k = kt * 32 + ((lane >> 4) << 3) + j;
    P[i] = f2bf(W_et[(k >> 7) * 16384 + c * 128 + (k & 127)]);
  }
}

// ---------- CSR build over merged graph ----------
__global__ void k_hist(const int* __restrict__ dst1, const int* __restrict__ dst2,
                       int E, int N, int* __restrict__ deg) {
  for (int e = blockIdx.x * blockDim.x + threadIdx.x; e < 2 * E; e += gridDim.x * blockDim.x) {
    int d = (e < E) ? dst1[e] : dst2[e - E] + N;
    atomicAdd(&deg[d], 1);
  }
}

__global__ __launch_bounds__(256) void k_scan_a(const int* __restrict__ deg, int n,
                                                int* __restrict__ bsum) {
  int base = blockIdx.x * 1024 + threadIdx.x * 4;
  int s = 0;
  if (base + 3 < n) {
    int4 v = *(const int4*)(deg + base);
    s = v.x + v.y + v.z + v.w;
  } else {
    for (int k = 0; k < 4; ++k) if (base + k < n) s += deg[base + k];
  }
  #pragma unroll
  for (int off = 32; off; off >>= 1) s += __shfl_xor(s, off);
  __shared__ int ws[4];
  if ((threadIdx.x & 63) == 0) ws[threadIdx.x >> 6] = s;
  __syncthreads();
  if (threadIdx.x == 0) bsum[blockIdx.x] = ws[0] + ws[1] + ws[2] + ws[3];
}

__global__ __launch_bounds__(1024) void k_scan_b(const int* __restrict__ bsum,
                                                 int* __restrict__ boffs, int nb) {
  int tid = threadIdx.x;
  int v = (tid < nb) ? bsum[tid] : 0;
  int lane = tid & 63, wv = tid >> 6;
  int x = v;
  #pragma unroll
  for (int off = 1; off < 64; off <<= 1) {
    int y = __shfl_up(x, off);
    if (lane >= off) x += y;
  }
  __shared__ int wsum[16];
  if (lane == 63) wsum[wv] = x;
  __syncthreads();
  if (tid < 16) {
    int u = wsum[tid];
    #pragma unroll
    for (int off = 1; off < 16; off <<= 1) {
      int y = __shfl_up(u, off);
      if (tid >= off) u += y;
    }
    wsum[tid] = u;
  }
  __syncthreads();
  int woff = wv ? wsum[wv - 1] : 0;
  if (tid < nb) boffs[tid] = woff + x - v;
}

__global__ __launch_bounds__(256) void k_scan_c(const int* __restrict__ deg,
    const int* __restrict__ boffs, int* __restrict__ row_ofs,
    int* __restrict__ cursor, int n) {
  int base = blockIdx.x * 1024 + threadIdx.x * 4;
  int v[4] = {0, 0, 0, 0};
  if (base + 3 < n) {
    int4 t = *(const int4*)(deg + base);
    v[0] = t.x; v[1] = t.y; v[2] = t.z; v[3] = t.w;
  } else {
    for (int k = 0; k < 4; ++k) if (base + k < n) v[k] = deg[base + k];
  }
  int s = v[0] + v[1] + v[2] + v[3];
  int lane = threadIdx.x & 63, wv = threadIdx.x >> 6;
  int x = s;
  #pragma unroll
  for (int off = 1; off < 64; off <<= 1) {
    int y = __shfl_up(x, off);
    if (lane >= off) x += y;
  }
  __shared__ int wsum[4];
  if (lane == 63) wsum[wv] = x;
  __syncthreads();
  int woff = 0;
  for (int w = 0; w < wv; ++w) woff += wsum[w];
  int run = boffs[blockIdx.x] + woff + x - s;
  #pragma unroll
  for (int k = 0; k < 4; ++k) {
    int i = base + k;
    if (i < n) {
      cursor[i] = run;
      run += v[k];
      row_ofs[i + 1] = run;
    }
  }
  if (blockIdx.x == 0 && threadIdx.x == 0) row_ofs[0] = 0;
}

// scatter: single merged array csr_se = src*4 + etype
__global__ void k_scatter(const int* __restrict__ src1, const int* __restrict__ dst1,
                          const int* __restrict__ ety1, const int* __restrict__ src2,
                          const int* __restrict__ dst2, const int* __restrict__ ety2,
                          int E, int N, int* __restrict__ cursor,
                          int* __restrict__ csr_se) {
  for (int e = blockIdx.x * blockDim.x + threadIdx.x; e < 2 * E; e += gridDim.x * blockDim.x) {
    int s, d, et;
    if (e < E) { s = src1[e]; d = dst1[e]; et = ety1[e]; }
    else { s = src2[e - E] + N; d = dst2[e - E] + N; et = ety2[e - E]; }
    int p = atomicAdd(&cursor[d], 1);
    csr_se[p] = s * 4 + et;
  }
}

// ---------- merged gid array [2N] + per-graph counts [128] ----------
__global__ void k_fillgid(const int* __restrict__ gid1, const int* __restrict__ gid2,
                          int N, int* __restrict__ gidc, int* __restrict__ gcnt) {
  __shared__ int cnt[NG2];
  int t = threadIdx.x;
  if (t < NG2) cnt[t] = 0;
  __syncthreads();
  int i = blockIdx.x * 256 + t;
  if (i < 2 * N) {
    int g = (i < N) ? gid1[i] : gid2[i - N] + NG;
    gidc[i] = g;
    atomicAdd(&cnt[g], 1);
  }
  __syncthreads();
  if (t < NG2 && cnt[t]) atomicAdd(&gcnt[t], cnt[t]);
}

// ---------- per-etype neighbor sums + counts; readlane, 8x + 4x + 1x MLP tiers ----------
__global__ __launch_bounds__(256) void k_aggS(const short* __restrict__ hb,
    const int* __restrict__ row_ofs, const int* __restrict__ csr_se,
    short* __restrict__ S, float* __restrict__ cntf, int N) {
  int node = blockIdx.x * 4 + (threadIdx.x >> 6);
  int lane = threadIdx.x & 63;
  if (node >= N) return;
  int beg = row_ofs[node], end = row_ofs[node + 1];
  float a0x = 0.f, a0y = 0.f, a1x = 0.f, a1y = 0.f;
  float a2x = 0.f, a2y = 0.f, a3x = 0.f, a3y = 0.f;
  int c0 = 0, c1 = 0, c2 = 0, c3 = 0;
  #define ACC(ET, VX, VY) do { \
      if (ET == 0)      { a0x += VX; a0y += VY; ++c0; } \
      else if (ET == 1) { a1x += VX; a1y += VY; ++c1; } \
      else if (ET == 2) { a2x += VX; a2y += VY; ++c2; } \
      else              { a3x += VX; a3y += VY; ++c3; } } while (0)
  for (int base = beg; base < end; base += 64) {
    int nv = end - base; if (nv > 64) nv = 64;
    int r = (lane < nv) ? csr_se[base + lane] : 0;
    int j = 0;
    for (; j + 8 <= nv; j += 8) {
      int rr0 = __builtin_amdgcn_readlane(r, j + 0);
      int rr1 = __builtin_amdgcn_readlane(r, j + 1);
      int rr2 = __builtin_amdgcn_readlane(r, j + 2);
      int rr3 = __builtin_amdgcn_readlane(r, j + 3);
      int rr4 = __builtin_amdgcn_readlane(r, j + 4);
      int rr5 = __builtin_amdgcn_readlane(r, j + 5);
      int rr6 = __builtin_amdgcn_readlane(r, j + 6);
      int rr7 = __builtin_amdgcn_readlane(r, j + 7);
      unsigned v0 = ((const unsigned*)(hb + (size_t)(rr0 >> 2) * 128))[lane];
      unsigned v1 = ((const unsigned*)(hb + (size_t)(rr1 >> 2) * 128))[lane];
      unsigned v2 = ((const unsigned*)(hb + (size_t)(rr2 >> 2) * 128))[lane];
      unsigned v3 = ((const unsigned*)(hb + (size_t)(rr3 >> 2) * 128))[lane];
      unsigned v4 = ((const unsigned*)(hb + (size_t)(rr4 >> 2) * 128))[lane];
      unsigned v5 = ((const unsigned*)(hb + (size_t)(rr5 >> 2) * 128))[lane];
      unsigned v6 = ((const unsigned*)(hb + (size_t)(rr6 >> 2) * 128))[lane];
      unsigned v7 = ((const unsigned*)(hb + (size_t)(rr7 >> 2) * 128))[lane];
      ACC(rr0 & 3, bflo(v0), bfhi(v0));
      ACC(rr1 & 3, bflo(v1), bfhi(v1));
      ACC(rr2 & 3, bflo(v2), bfhi(v2));
      ACC(rr3 & 3, bflo(v3), bfhi(v3));
      ACC(rr4 & 3, bflo(v4), bfhi(v4));
      ACC(rr5 & 3, bflo(v5), bfhi(v5));
      ACC(rr6 & 3, bflo(v6), bfhi(v6));
      ACC(rr7 & 3, bflo(v7), bfhi(v7));
    }
    for (; j + 4 <= nv; j += 4) {
      int rr0 = __builtin_amdgcn_readlane(r, j + 0);
      int rr1 = __builtin_amdgcn_readlane(r, j + 1);
      int rr2 = __builtin_amdgcn_readlane(r, j + 2);
      int rr3 = __builtin_amdgcn_readlane(r, j + 3);
      unsigned v0 = ((const unsigned*)(hb + (size_t)(rr0 >> 2) * 128))[lane];
      unsigned v1 = ((const unsigned*)(hb + (size_t)(rr1 >> 2) * 128))[lane];
      unsigned v2 = ((const unsigned*)(hb + (size_t)(rr2 >> 2) * 128))[lane];
      unsigned v3 = ((const unsigned*)(hb + (size_t)(rr3 >> 2) * 128))[lane];
      ACC(rr0 & 3, bflo(v0), bfhi(v0));
      ACC(rr1 & 3, bflo(v1), bfhi(v1));
      ACC(rr2 & 3, bflo(v2), bfhi(v2));
      ACC(rr3 & 3, bflo(v3), bfhi(v3));
    }
    for (; j < nv; ++j) {
      int rr = __builtin_amdgcn_readlane(r, j);
      unsigned v = ((const unsigned*)(hb + (size_t)(rr >> 2) * 128))[lane];
      ACC(rr & 3, bflo(v), bfhi(v));
    }
  }
  #undef ACC
  size_t b = (size_t)node * 512;
  ((unsigned*)(S + b      ))[lane] = pk2(a0x, a0y);
  ((unsigned*)(S + b + 128))[lane] = pk2(a1x, a1y);
  ((unsigned*)(S + b + 256))[lane] = pk2(a2x, a2y);
  ((unsigned*)(S + b + 384))[lane] = pk2(a3x, a3y);
  if (lane == 0) {
    float4 cv = {(float)c0, (float)c1, (float)c2, (float)c3};
    *(float4*)(cntf + (size_t)node * 4) = cv;
  }
}

// ---------- a = S[M,512] @ Wa (K=512 MFMA) + cnt_et·b_et  -> ab (bf16) ----------
__global__ __launch_bounds__(256) void k_agemm(const short* __restrict__ S,
    const short* __restrict__ WaP, const float* __restrict__ b_et,
    const float* __restrict__ cntf, short* __restrict__ ab, int M) {
  int tid = threadIdx.x;
  int lane = tid & 63, wave = tid >> 6;
  int row0 = blockIdx.x * 64 + wave * 16;
  int quad = lane >> 4, l15 = lane & 15;
  int ar = row0 + l15; if (ar >= M) ar = M - 1;
  short8 sf[16];
  #pragma unroll
  for (int kt = 0; kt < 16; ++kt)
    sf[kt] = *(const short8*)(S + (size_t)ar * 512 + kt * 32 + quad * 8);
  float4 cn[4];
  #pragma unroll
  for (int reg = 0; reg < 4; ++reg) {
    int r = row0 + quad * 4 + reg; if (r >= M) r = M - 1;
    cn[reg] = *(const float4*)(cntf + (size_t)r * 4);
  }
  for (int nt = 0; nt < 8; ++nt) {
    f32x4 acc = {0.f, 0.f, 0.f, 0.f};
    #pragma unroll
    for (int kt = 0; kt < 16; ++kt) {
      short8 b = *(const short8*)(WaP + (((size_t)(nt * 16 + kt) * 64) + lane) * 8);
      acc = __builtin_amdgcn_mfma_f32_16x16x32_bf16(sf[kt], b, acc, 0, 0, 0);
    }
    int c = nt * 16 + l15;
    float be0 = b_et[c], be1 = b_et[128 + c], be2 = b_et[256 + c], be3 = b_et[384 + c];
    #pragma unroll
    for (int reg = 0; reg < 4; ++reg) {
      int r = row0 + quad * 4 + reg;
      if (r < M) {
        float v = acc[reg] + cn[reg].x * be0 + cn[reg].y * be1
                           + cn[reg].z * be2 + cn[reg].w * be3;
        ab[(size_t)r * 128 + c] = f2bf(v);
      }
    }
  }
}

// ---------- fused GRU via MFMA, 32 rows/wave, bf16 recurrent state ----------
__global__ __launch_bounds__(256) void k_gru_mfma(const short* __restrict__ ab,
    short* __restrict__ hb,
    const short* __restrict__ Pih, const short* __restrict__ Phh,
    const float* __restrict__ b_ih, const float* __restrict__ b_hh, int M) {
  int tid = threadIdx.x;
  int lane = tid & 63, wave = tid >> 6;
  int row0 = blockIdx.x * 128 + wave * 32;
  int quad = lane >> 4, l15 = lane & 15;
  short8 fa[2][4], fh[2][4];
  #pragma unroll
  for (int rt = 0; rt < 2; ++rt) {
    int ar = row0 + rt * 16 + l15; if (ar >= M) ar = M - 1;
    #pragma unroll
    for (int kt = 0; kt < 4; ++kt) {
      fa[rt][kt] = *(const short8*)(ab + (size_t)ar * 128 + kt * 32 + quad * 8);
      fh[rt][kt] = *(const short8*)(hb + (size_t)ar * 128 + kt * 32 + quad * 8);
    }
  }
  for (int nt = 0; nt < 8; ++nt) {
    f32x4 accr[2], accz[2], acci[2], acch[2];
    #pragma unroll
    for (int rt = 0; rt < 2; ++rt) {
      accr[rt] = {0.f,0.f,0.f,0.f}; accz[rt] = {0.f,0.f,0.f,0.f};
      acci[rt] = {0.f,0.f,0.f,0.f}; acch[rt] = {0.f,0.f,0.f,0.f};
    }
    #pragma unroll
    for (int kt = 0; kt < 4; ++kt) {
      size_t li = ((size_t)lane) * 8;
      short8 wr = *(const short8*)(Pih + ((size_t)((nt     ) * 4 + kt) * 64) * 8 + li);
      short8 wz = *(const short8*)(Pih + ((size_t)((nt +  8) * 4 + kt) * 64) * 8 + li);
      short8 wn = *(const short8*)(Pih + ((size_t)((nt + 16) * 4 + kt) * 64) * 8 + li);
      short8 ur = *(const short8*)(Phh + ((size_t)((nt     ) * 4 + kt) * 64) * 8 + li);
      short8 uz = *(const short8*)(Phh + ((size_t)((nt +  8) * 4 + kt) * 64) * 8 + li);
      short8 un = *(const short8*)(Phh + ((size_t)((nt + 16) * 4 + kt) * 64) * 8 + li);
      #pragma unroll
      for (int rt = 0; rt < 2; ++rt) {
        accr[rt] = __builtin_amdgcn_mfma_f32_16x16x32_bf16(fa[rt][kt], wr, accr[rt], 0, 0, 0);
        accr[rt] = __builtin_amdgcn_mfma_f32_16x16x32_bf16(fh[rt][kt], ur, accr[rt], 0, 0, 0);
        accz[rt] = __builtin_amdgcn_mfma_f32_16x16x32_bf16(fa[rt][kt], wz, accz[rt], 0, 0, 0);
        accz[rt] = __builtin_amdgcn_mfma_f32_16x16x32_bf16(fh[rt][kt], uz, accz[rt], 0, 0, 0);
        acci[rt] = __builtin_amdgcn_mfma_f32_16x16x32_bf16(fa[rt][kt], wn, acci[rt], 0, 0, 0);
        acch[rt] = __builtin_amdgcn_mfma_f32_16x16x32_bf16(fh[rt][kt], un, acch[rt], 0, 0, 0);
      }
    }
    int c = nt * 16 + l15;
    float bir = b_ih[c],      bhr = b_hh[c];
    float biz = b_ih[c+128],  bhz = b_hh[c+128];
    float bin_= b_ih[c+256],  bhn = b_hh[c+256];
    #pragma unroll
    for (int rt = 0; rt < 2; ++rt) {
      #pragma unroll
      for (int reg = 0; reg < 4; ++reg) {
        int r = row0 + rt * 16 + quad * 4 + reg;
        if (r < M) {
          float rg = sigf(accr[rt][reg] + bir + bhr);
          float zg = sigf(accz[rt][reg] + biz + bhz);
          float ng = tanhf_fast(acci[rt][reg] + bin_ + rg * (acch[rt][reg] + bhn));
          float hold = bf2f(hb[(size_t)r * 128 + c]);
          float hn2 = (1.f - zg) * ng + zg * hold;
          hb[(size_t)r * 128 + c] = f2bf(hn2);
        }
      }
    }
  }
}

// ---------- fc GEMM (256 cols) fused normalize+sigmoid + el/er; zq out is fp8 ----------
__global__ __launch_bounds__(256) void k_fc_eler(const short* __restrict__ Ab,
    const short* __restrict__ Bp, const float* __restrict__ attn_l,
    const float* __restrict__ attn_r, unsigned char* __restrict__ zq,
    float* __restrict__ el, float* __restrict__ er, int M) {
  int tid = threadIdx.x;
  int lane = tid & 63, wave = tid >> 6;
  int row0 = blockIdx.x * 128 + wave * 32;
  int quad = lane >> 4, l15 = lane & 15;
  short8 af[2][4];
  #pragma unroll
  for (int rt = 0; rt < 2; ++rt) {
    int ar = row0 + rt * 16 + l15; if (ar >= M) ar = M - 1;
    #pragma unroll
    for (int kt = 0; kt < 4; ++kt)
      af[rt][kt] = *(const short8*)(Ab + (size_t)ar * 128 + kt * 32 + quad * 8);
  }
  #pragma unroll
  for (int rt = 0; rt < 2; ++rt) {
    float ss = 0.f;
    #pragma unroll
    for (int kt = 0; kt < 4; ++kt)
      #pragma unroll
      for (int j = 0; j < 8; ++j) {
        float x = bf2f(af[rt][kt][j]);
        ss += x * x;
      }
    ss += __shfl_xor(ss, 16);
    ss += __shfl_xor(ss, 32);
    float inv = 1.f / fmaxf(sqrtf(ss), 1e-12f);
    #pragma unroll
    for (int kt = 0; kt < 4; ++kt)
      #pragma unroll
      for (int j = 0; j < 8; ++j)
        af[rt][kt][j] = f2bf(sigf(bf2f(af[rt][kt][j]) * inv));
  }
  float elp[2][2][4] = {};
  float erp[2][2][4] = {};
  for (int nt = 0; nt < 16; ++nt) {
    f32x4 a0 = {0.f,0.f,0.f,0.f}, a1 = {0.f,0.f,0.f,0.f};
    #pragma unroll
    for (int kt = 0; kt < 4; ++kt) {
      short8 b = *(const short8*)(Bp + (((size_t)(nt * 4 + kt) * 64) + lane) * 8);
      a0 = __builtin_amdgcn_mfma_f32_16x16x32_bf16(af[0][kt], b, a0, 0, 0, 0);
      a1 = __builtin_amdgcn_mfma_f32_16x16x32_bf16(af[1][kt], b, a1, 0, 0, 0);
    }
    int head = nt >> 3;
    int colh = (nt & 7) * 16 + l15;
    float alv = attn_l[head * 128 + colh];
    float arv = attn_r[head * 128 + colh];
    int c = nt * 16 + l15;
    #pragma unroll
    for (int rt = 0; rt < 2; ++rt) {
      f32x4 acc = rt ? a1 : a0;
      #pragma unroll
      for (int reg = 0; reg < 4; ++reg) {
        int r = row0 + rt * 16 + quad * 4 + reg;
        if (r < M) zq[(size_t)r * 256 + c] = f2fp8(acc[reg]);
        elp[rt][head][reg] += acc[reg] * alv;
        erp[rt][head][reg] += acc[reg] * arv;
      }
    }
  }
  #pragma unroll
  for (int off = 1; off < 16; off <<= 1) {
    #pragma unroll
    for (int rt = 0; rt < 2; ++rt)
      #pragma unroll
      for (int h = 0; h < 2; ++h)
        #pragma unroll
        for (int reg = 0; reg < 4; ++reg) {
          elp[rt][h][reg] += __shfl_xor(elp[rt][h][reg], off);
          erp[rt][h][reg] += __shfl_xor(erp[rt][h][reg], off);
        }
  }
  if (l15 == 0) {
    #pragma unroll
    for (int rt = 0; rt < 2; ++rt)
      #pragma unroll
      for (int h = 0; h < 2; ++h)
        #pragma unroll
        for (int reg = 0; reg < 4; ++reg) {
          int r = row0 + rt * 16 + quad * 4 + reg;
          if (r < M) {
            el[r * 2 + h] = elp[rt][h][reg];
            er[r * 2 + h] = erp[rt][h][reg];
          }
        }
  }
}

// ---------- GAT aggregation: no-max softmax (scores bounded) + packed bf16 weight
// broadcast (1 shfl/edge). fp8 z gather, bf16 out. ----------
__global__ __launch_bounds__(256) void k_gat(const unsigned char* __restrict__ zq,
    const float* __restrict__ el, const float* __restrict__ er,
    const int* __restrict__ row_ofs, const int* __restrict__ csr_se,
    const float* __restrict__ gat_bias, short* __restrict__ outb, int N) {
  int node = blockIdx.x * 4 + (threadIdx.x >> 6);
  int lane = threadIdx.x & 63;
  if (node >= N) return;
  int beg = row_ofs[node], end = row_ofs[node + 1];
  float2 ern = ((const float2*)er)[node];
  float l0 = 0.f, l1 = 0.f;
  float4 acc = {0.f, 0.f, 0.f, 0.f};
  int head = lane >> 5;
  for (int base = beg; base < end; base += 64) {
    int nv = end - base; if (nv > 64) nv = 64;
    int sidx = (lane < nv) ? (csr_se[base + lane] >> 2) : 0;
    float p0 = 0.f, p1 = 0.f;
    if (lane < nv) {
      float2 els = ((const float2*)el)[sidx];
      p0 = expf(lrelu(els.x + ern.x));   // |score| <= ~20 -> exp safe in fp32
      p1 = expf(lrelu(els.y + ern.y));
    }
    float t0 = p0, t1 = p1;
    #pragma unroll
    for (int off = 32; off; off >>= 1) { t0 += __shfl_xor(t0, off); t1 += __shfl_xor(t1, off); }
    l0 += t0; l1 += t1;
    int w01 = (int)pk2(p0, p1);          // bf16-packed per-edge weights
    #pragma unroll 4
    for (int j = 0; j < nv; ++j) {
      int sj = __shfl(sidx, j);
      unsigned wj = (unsigned)__shfl(w01, j);
      float w = head ? bfhi(wj) : bflo(wj);
      unsigned zv = ((const unsigned*)(zq + (size_t)sj * 256))[lane];
      f32x2 lo = __builtin_amdgcn_cvt_pk_f32_fp8(zv, false);
      f32x2 hi = __builtin_amdgcn_cvt_pk_f32_fp8(zv, true);
      acc.x += w * lo[0]; acc.y += w * lo[1];
      acc.z += w * hi[0]; acc.w += w * hi[1];
    }
  }
  float inv0 = (l0 > 0.f) ? 1.f / l0 : 0.f;
  float inv1 = (l1 > 0.f) ? 1.f / l1 : 0.f;
  float inv = head ? inv1 : inv0;
  float4 b = ((const float4*)gat_bias)[lane];
  float ox = fmaxf(acc.x * inv + b.x, 0.f);
  float oy = fmaxf(acc.y * inv + b.y, 0.f);
  float oz = fmaxf(acc.z * inv + b.z, 0.f);
  float ow = fmaxf(acc.w * inv + b.w, 0.f);
  ((uint2*)(outb + (size_t)node * 256))[lane] = make_uint2(pk2(ox, oy), pk2(oz, ow));
}

// ---------- parallel segmented per-graph sums (bf16 input) ----------
__global__ __launch_bounds__(256) void k_segred(const short* __restrict__ hgatb,
    const int* __restrict__ gidc, float* __restrict__ sums, int NT2) {
  int node0 = blockIdx.x * 128;
  int col = threadIdx.x;
  int end = node0 + 128; if (end > NT2) end = NT2;
  if (node0 >= NT2) return;
  float acc = 0.f;
  int gcur = gidc[node0];
  for (int n = node0; n < end; ++n) {
    int g = gidc[n];
    if (g != gcur) {
      atomicAdd(&sums[gcur * 256 + col], acc);
      acc = 0.f; gcur = g;
    }
    acc += bf2f(hgatb[(size_t)n * 256 + col]);
  }
  atomicAdd(&sums[gcur * 256 + col], acc);
}

// ---------- mean + classifier ----------
__global__ __launch_bounds__(64) void k_classify(const float* __restrict__ sums,
    const int* __restrict__ gcnt, const float* __restrict__ W_cls,
    const float* __restrict__ b_cls, float* __restrict__ logits) {
  int g = blockIdx.x, tid = threadIdx.x;
  int hh = tid >> 5, c = tid & 31;
  float invc = 1.f / fmaxf((float)gcnt[g], 1.f);
  float acc = 0.f;
  for (int d = 0; d < D; ++d)
    acc += (sums[g * 256 + hh * D + d] * invc) * W_cls[c * D + d];
  logits[g * 64 + hh * 32 + c] = acc + b_cls[c];
}

// ---------- pairwise distance + softmax over heads (graph g vs g+64) ----------
__global__ __launch_bounds__(64) void k_final(const float* __restrict__ logits,
    float* __restrict__ out) {
  int g = threadIdx.x;
  if (g >= NG) return;
  float d[2];
  #pragma unroll
  for (int hh = 0; hh < 2; ++hh) {
    float s = 0.f;
    for (int c = 0; c < 32; ++c) {
      float df = logits[g * 64 + hh * 32 + c] - logits[(g + NG) * 64 + hh * 32 + c] + 1e-6f;
      s += df * df;
    }
    d[hh] = sqrtf(s);
  }
  float mx = fmaxf(d[0], d[1]);
  float e0 = expf(d[0] - mx), e1 = expf(d[1] - mx);
  float den = e0 + e1;
  out[g * 2] = e0 / den;
  out[g * 2 + 1] = e1 / den;
}

extern "C" void kernel_launch(void* const* d_in, const int* in_sizes, int n_in,
                              void* d_out, int out_size, void* d_ws, size_t ws_size,
                              hipStream_t stream) {
  const float* in_feat1 = (const float*)d_in[0];
  const float* in_feat2 = (const float*)d_in[1];
  const int* src1 = (const int*)d_in[2];
  const int* dst1 = (const int*)d_in[3];
  const int* ety1 = (const int*)d_in[4];
  const int* gid1 = (const int*)d_in[5];
  const int* src2 = (const int*)d_in[6];
  const int* dst2 = (const int*)d_in[7];
  const int* ety2 = (const int*)d_in[8];
  const int* gid2 = (const int*)d_in[9];
  const float* W_et = (const float*)d_in[10];
  const float* b_et = (const float*)d_in[11];
  const float* W_ih = (const float*)d_in[12];
  const float* W_hh = (const float*)d_in[13];
  const float* b_ih = (const float*)d_in[14];
  const float* b_hh = (const float*)d_in[15];
  const float* W_fc = (const float*)d_in[16];
  const float* attn_l = (const float*)d_in[17];
  const float* attn_r = (const float*)d_in[18];
  const float* gat_bias = (const float*)d_in[19];
  const float* W_cls = (const float*)d_in[20];
  const float* b_cls = (const float*)d_in[21];
  float* out = (float*)d_out;

  int N = in_sizes[0] / D;
  int E = in_sizes[2];
  int N2 = 2 * N, E2 = 2 * E;

  char* p = (char*)d_ws;
  auto alloc = [&](size_t bytes) -> void* {
    char* r = p;
    p += (bytes + 255) & ~(size_t)255;
    return (void*)r;
  };
  short* WaP  = (short*)alloc((size_t)512 * 128 * 2);
  short* WihP = (short*)alloc((size_t)384 * 128 * 2);
  short* WhhP = (short*)alloc((size_t)384 * 128 * 2);
  short* WfcP = (short*)alloc((size_t)256 * 128 * 2);
  short* hb  = (short*)alloc((size_t)N2 * D * 2);
  short* ab  = (short*)alloc((size_t)N2 * D * 2);
  short* S   = (short*)alloc((size_t)N2 * 512 * 2);     // per-etype h sums; hgatb overlays
  unsigned char* zq = (unsigned char*)alloc((size_t)N2 * 256); // fp8 zft
  float* el  = (float*)alloc((size_t)N2 * 2 * 4);
  float* er  = (float*)alloc((size_t)N2 * 2 * 4);
  float* cntf= (float*)alloc((size_t)N2 * 4 * 4);
  float* sums= (float*)alloc((size_t)NG2 * 256 * 4);
  float* logits = (float*)alloc((size_t)NG2 * 64 * 4);
  int* deg     = (int*)alloc((size_t)N2 * 4);
  int* row_ofs = (int*)alloc(((size_t)N2 + 1) * 4);
  int* cursor  = (int*)alloc((size_t)N2 * 4);
  int* gidc    = (int*)alloc((size_t)N2 * 4);
  int* gcnt    = (int*)alloc((size_t)NG2 * 4);
  int* bsum    = (int*)alloc((size_t)1024 * 4);
  int* boffs   = (int*)alloc((size_t)1024 * 4);
  int* csr_se  = (int*)alloc((size_t)E2 * 4);
  if ((size_t)(p - (char*)d_ws) > ws_size) return;

  short* hgatb = S;   // [N2,256] bf16 — overlays S (dead after last k_agemm)

  // weight packing
  k_packA512<<<dim3(32), dim3(256), 0, stream>>>(W_et, WaP);
  k_pack<<<dim3(48), dim3(256), 0, stream>>>(W_ih, WihP, 384);
  k_pack<<<dim3(48), dim3(256), 0, stream>>>(W_hh, WhhP, 384);
  k_pack<<<dim3(32), dim3(256), 0, stream>>>(W_fc, WfcP, 256);

  // CSR for merged graph
  hipMemsetAsync(deg, 0, (size_t)N2 * 4, stream);
  hipMemsetAsync(gcnt, 0, (size_t)NG2 * 4, stream);
  int eb = (E2 + 255) / 256;
  int nb = (N2 + 1023) / 1024;
  k_hist<<<dim3(eb), dim3(256), 0, stream>>>(dst1, dst2, E, N, deg);
  k_scan_a<<<dim3(nb), dim3(256), 0, stream>>>(deg, N2, bsum);
  k_scan_b<<<dim3(1), dim3(1024), 0, stream>>>(bsum, boffs, nb);
  k_scan_c<<<dim3(nb), dim3(256), 0, stream>>>(deg, boffs, row_ofs, cursor, N2);
  k_scatter<<<dim3(eb), dim3(256), 0, stream>>>(src1, dst1, ety1, src2, dst2, ety2,
                                                E, N, cursor, csr_se);
  k_fillgid<<<dim3((N2 + 255) / 256), dim3(256), 0, stream>>>(gid1, gid2, N, gidc, gcnt);

  // init h (bf16)
  k_init<<<dim3(1024), dim3(256), 0, stream>>>(in_feat1, in_feat2, hb, N * D / 4);

  int gb64 = (N2 + 63) / 64;
  int gb128 = (N2 + 127) / 128;
  int nb4 = (N2 + 3) / 4;

  for (int s = 0; s < NSTEPS; ++s) {
    k_aggS<<<dim3(nb4), dim3(256), 0, stream>>>(hb, row_ofs, csr_se, S, cntf, N2);
    k_agemm<<<dim3(gb64), dim3(256), 0, stream>>>(S, WaP, b_et, cntf, ab, N2);
    k_gru_mfma<<<dim3(gb128), dim3(256), 0, stream>>>(ab, hb, WihP, WhhP, b_ih, b_hh, N2);
  }
  k_fc_eler<<<dim3(gb128), dim3(256), 0, stream>>>(hb, WfcP, attn_l, attn_r, zq, el, er, N2);
  k_gat<<<dim3(nb4), dim3(256), 0, stream>>>(zq, el, er, row_ofs, csr_se,
                                             gat_bias, hgatb, N2);
  hipMemsetAsync(sums, 0, (size_t)NG2 * 256 * 4, stream);
  k_segred<<<dim3((N2 + 127) / 128), dim3(256), 0, stream>>>(hgatb, gidc, sums, N2);
  k_classify<<<dim3(NG2), dim3(64), 0, stream>>>(sums, gcnt, W_cls, b_cls, logits);
  k_final<<<dim3(1), dim3(64), 0, stream>>>(logits, out);
}